// Round 2
// baseline (12975.879 us; speedup 1.0000x reference)
//
#include <hip/hip_runtime.h>
#include <cstdint>
#include <cstddef>

typedef _Float16 half2_t __attribute__((ext_vector_type(2)));
typedef _Float16 half4_t __attribute__((ext_vector_type(4)));
typedef _Float16 half8_t __attribute__((ext_vector_type(8)));
typedef float    float4_t __attribute__((ext_vector_type(4)));

#define CAPLEN 65
#define PLDSROWS 128   // P rows pinned in LDS per block (wave-aligned)
#define PTLD 200       // P_T row stride in halfs (196 used, 400B, 16B-aligned)

#if defined(__has_builtin)
#if __has_builtin(__builtin_amdgcn_fdot2)
#define HAS_FDOT2 1
#endif
#endif

__device__ __forceinline__ float fdot2f(half2_t a, half2_t b, float c) {
#ifdef HAS_FDOT2
  return __builtin_amdgcn_fdot2(a, b, c, false);
#else
  return c + (float)a[0]*(float)b[0] + (float)a[1]*(float)b[1];
#endif
}

__device__ __forceinline__ float fast_tanh(float x) {
  float e = __expf(2.f*x);
  return 1.f - 2.f/(e + 1.f);
}
__device__ __forceinline__ float fast_sig(float x) {
  return 1.f/(1.f + __expf(-x));
}

// ---------- fp32 -> fp16 convert (n % 4 == 0) ----------
__global__ void cvt_k(const float* __restrict__ s, _Float16* __restrict__ d, int n) {
  int i = (blockIdx.x*blockDim.x + threadIdx.x)*4;
  if (i < n) {
    float4 v = *(const float4*)(s + i);
    half4_t h;
    h[0] = (_Float16)v.x; h[1] = (_Float16)v.y; h[2] = (_Float16)v.z; h[3] = (_Float16)v.w;
    *(half4_t*)(d + i) = h;
  }
}

// bias sum + zero the group-barrier state (32 groups x 32 uints)
__global__ void bias_sum_k(const float* __restrict__ a, const float* __restrict__ b,
                           float* __restrict__ o, unsigned* __restrict__ bar) {
  int i = blockIdx.x*blockDim.x + threadIdx.x;
  if (i < 2048) o[i] = a[i] + b[i];
  if (i < 1024) bar[i] = 0u;
}

// gather embeddings for all (t,b): row r = t*32 + b, token = captions[b][t]
__global__ void gather_emb_k(const float* __restrict__ emb, const int* __restrict__ cap,
                             _Float16* __restrict__ X) {
  int r = blockIdx.x;
  int t = r >> 5, b = r & 31;
  int tok = cap[b*CAPLEN + t];
  const float* s = emb + (size_t)tok*512;
  _Float16* d = X + (size_t)r*512;
  for (int k = threadIdx.x; k < 512; k += blockDim.x) d[k] = (_Float16)s[k];
}

// feat_mean -> h0 (fp16), c0 (fp32); one wg per batch element
__global__ void init_state_k(const float* __restrict__ imgf,
                             const float* __restrict__ Wh0, const float* __restrict__ bh0,
                             const float* __restrict__ Wc0, const float* __restrict__ bc0,
                             float* __restrict__ c_state, _Float16* __restrict__ h0h) {
  __shared__ float fm[512];
  int b = blockIdx.x, tid = threadIdx.x;
  for (int dI = tid; dI < 512; dI += blockDim.x) {
    float s = 0.f;
    const float* p = imgf + ((size_t)b*196)*512 + dI;
    for (int n = 0; n < 196; n++) s += p[(size_t)n*512];
    fm[dI] = s * (1.f/196.f);
  }
  __syncthreads();
  for (int dI = tid; dI < 512; dI += blockDim.x) {
    const float* wh = Wh0 + (size_t)dI*512;
    const float* wc = Wc0 + (size_t)dI*512;
    float h = bh0[dI], c = bc0[dI];
    for (int k = 0; k < 512; k++) { h += fm[k]*wh[k]; c += fm[k]*wc[k]; }
    h0h[b*512 + dI] = (_Float16)h;
    c_state[b*512 + dI] = c;
  }
}

// Generic C = A * B^T (+bias), fp16 in, fp32 acc, MFMA 16x16x32.
// MODE 0: fp32 C (+bias). MODE 1: fp16 C.
template<int MODE>
__global__ void __launch_bounds__(256) gemm_abt_k(const _Float16* __restrict__ A, int lda,
    const _Float16* __restrict__ B, int ldb, void* __restrict__ Cp, int ldc,
    const float* __restrict__ bias, int K) {
  int wave = threadIdx.x >> 6, lane = threadIdx.x & 63;
  int m0 = blockIdx.y*128 + (wave >> 1)*64;
  int n0 = blockIdx.x*128 + (wave & 1)*64;
  int lr = lane & 15, quad = lane >> 4;
  float4_t acc[4][4];
  #pragma unroll
  for (int i = 0; i < 4; i++)
    #pragma unroll
    for (int j = 0; j < 4; j++)
      acc[i][j] = (float4_t){0.f, 0.f, 0.f, 0.f};
  const _Float16* Ap = A + (size_t)(m0 + lr)*lda + quad*8;
  const _Float16* Bp = B + (size_t)(n0 + lr)*ldb + quad*8;
  for (int k0 = 0; k0 < K; k0 += 32) {
    half8_t af[4], bf[4];
    #pragma unroll
    for (int i = 0; i < 4; i++) af[i] = *(const half8_t*)(Ap + (size_t)i*16*lda + k0);
    #pragma unroll
    for (int i = 0; i < 4; i++) bf[i] = *(const half8_t*)(Bp + (size_t)i*16*ldb + k0);
    #pragma unroll
    for (int mi = 0; mi < 4; mi++)
      #pragma unroll
      for (int ni = 0; ni < 4; ni++)
        acc[mi][ni] = __builtin_amdgcn_mfma_f32_16x16x32_f16(af[mi], bf[ni], acc[mi][ni], 0, 0, 0);
  }
  #pragma unroll
  for (int mi = 0; mi < 4; mi++) {
    #pragma unroll
    for (int ni = 0; ni < 4; ni++) {
      int col = n0 + ni*16 + lr;
      float bv = (MODE == 1) ? 0.f : bias[col];
      #pragma unroll
      for (int r = 0; r < 4; r++) {
        int row = m0 + mi*16 + quad*4 + r;
        if (MODE == 1) {
          ((_Float16*)Cp)[(size_t)row*ldc + col] = (_Float16)acc[mi][ni][r];
        } else {
          ((float*)Cp)[(size_t)row*ldc + col] = acc[mi][ni][r] + bv;
        }
      }
    }
  }
}

// P_T[b][row][n] = sum_k W_ih[row][512+k] * imgf[b][n][k]   (fp16 out, ldc=PTLD)
// grid (2, 16, 32): x = n-tile(128), y = m-tile(128), z = b
__global__ void __launch_bounds__(256) gemm_pt_k(const _Float16* __restrict__ A,
    const _Float16* __restrict__ Bimg, _Float16* __restrict__ Cpt) {
  int z = blockIdx.z;
  const _Float16* B = Bimg + (size_t)z*196*512;   // rows >=196 read OOB garbage; cols masked downstream
  _Float16* C = Cpt + (size_t)z*2048*PTLD;
  int wave = threadIdx.x >> 6, lane = threadIdx.x & 63;
  int m0 = blockIdx.y*128 + (wave >> 1)*64;
  int n0 = blockIdx.x*128 + (wave & 1)*64;
  int lr = lane & 15, quad = lane >> 4;
  float4_t acc[4][4];
  #pragma unroll
  for (int i = 0; i < 4; i++)
    #pragma unroll
    for (int j = 0; j < 4; j++)
      acc[i][j] = (float4_t){0.f, 0.f, 0.f, 0.f};
  const _Float16* Ap = A + (size_t)(m0 + lr)*1024 + quad*8;
  const _Float16* Bp = B + (size_t)(n0 + lr)*512 + quad*8;
  for (int k0 = 0; k0 < 512; k0 += 32) {
    half8_t af[4], bf[4];
    #pragma unroll
    for (int i = 0; i < 4; i++) af[i] = *(const half8_t*)(Ap + (size_t)i*16*1024 + k0);
    #pragma unroll
    for (int i = 0; i < 4; i++) bf[i] = *(const half8_t*)(Bp + (size_t)i*16*512 + k0);
    #pragma unroll
    for (int mi = 0; mi < 4; mi++)
      #pragma unroll
      for (int ni = 0; ni < 4; ni++)
        acc[mi][ni] = __builtin_amdgcn_mfma_f32_16x16x32_f16(af[mi], bf[ni], acc[mi][ni], 0, 0, 0);
  }
  #pragma unroll
  for (int mi = 0; mi < 4; mi++) {
    #pragma unroll
    for (int ni = 0; ni < 4; ni++) {
      int col = n0 + ni*16 + lr;
      if (col < PTLD) {
        #pragma unroll
        for (int r = 0; r < 4; r++) {
          int row = m0 + mi*16 + quad*4 + r;
          C[(size_t)row*PTLD + col] = (_Float16)acc[mi][ni][r];
        }
      }
    }
  }
}

// ---- 8-block group barrier (same proven fence structure as the r1 global barrier) ----
__device__ __forceinline__ void group_barrier(unsigned* __restrict__ gb) {
  __syncthreads();
  __threadfence();
  if (threadIdx.x == 0) {
    unsigned sense = __hip_atomic_load(gb + 1, __ATOMIC_RELAXED, __HIP_MEMORY_SCOPE_AGENT);
    unsigned a = __hip_atomic_fetch_add(gb, 1u, __ATOMIC_ACQ_REL, __HIP_MEMORY_SCOPE_AGENT) + 1u;
    if (a == 8u) {
      __hip_atomic_store(gb, 0u, __ATOMIC_RELAXED, __HIP_MEMORY_SCOPE_AGENT);
      __hip_atomic_store(gb + 1, sense + 1u, __ATOMIC_RELEASE, __HIP_MEMORY_SCOPE_AGENT);
    } else {
      while (__hip_atomic_load(gb + 1, __ATOMIC_ACQUIRE, __HIP_MEMORY_SCOPE_AGENT) == sense)
        __builtin_amdgcn_s_sleep(1);
    }
  }
  __syncthreads();
  __threadfence();
}

// ---- persistent recurrence: 32 independent groups of 8 blocks (one group per b) ----
// block: b = bid&31, r = bid>>5 (blocks of a group share bid%8 -> same XCD).
// Per step: P1: gacc = Xg + Whh.h (reg), hW slice -> hw_g | bar | P2: e rows -> e_g |
//           bar | P3: softmax (replicated) + gates (alpha.P from LDS/L2) + pointwise | bar
__global__ void __launch_bounds__(256) loop_k(
    const _Float16* __restrict__ Wdec_h,   // [512][512]
    const _Float16* __restrict__ Whh_h,    // [2048][512]
    const _Float16* __restrict__ fproj_h,  // [32][196][512]
    const _Float16* __restrict__ P_T,      // [32][2048][PTLD]
    const float*    __restrict__ Xg,       // [64*32][2048]
    const float*    __restrict__ v_att,    // [512]
    const float*    __restrict__ c_init,   // [32][512]
    _Float16*       __restrict__ hbuf,     // [32][512]
    float*          __restrict__ hw_g,     // [32][512]
    float*          __restrict__ e_g,      // [32][256]
    _Float16*       __restrict__ H_h,      // [64*32][512]
    float*          __restrict__ out_alpha,// [32][64][196]
    unsigned*       __restrict__ bar) {
  __shared__ _Float16 P_lds[196*PLDSROWS]; // [n][tid], rows tid<128
  __shared__ _Float16 hl[512];
  __shared__ float vl[512];
  __shared__ float hwl[512];
  __shared__ float redA[256];
  __shared__ float sa[256];
  __shared__ float ep[32][9];
  __shared__ float sm_g[256];
  int bid = blockIdx.x, tid = threadIdx.x;
  int b = bid & 31, r = bid >> 5;
  unsigned* gbar = bar + b*32;
  int typ = tid >> 6, dl = tid & 63;
  int grow = typ*512 + r*64 + dl;          // this thread's gate row

  for (int i = tid; i < 512; i += 256) vl[i] = v_att[i];
  float c_reg = (tid < 64) ? c_init[b*512 + r*64 + tid] : 0.f;

  // stage pinned P rows into LDS (once): P_lds[n][tid] = P_T[b][grow][n]
  {
    const _Float16* pp = P_T + ((size_t)b*2048 + grow)*PTLD;
    if (tid < PLDSROWS) {
      for (int k8 = 0; k8 < 24; k8++) {
        half8_t v8 = *(const half8_t*)(pp + k8*8);
        #pragma unroll
        for (int j = 0; j < 8; j++) P_lds[(k8*8+j)*PLDSROWS + tid] = v8[j];
      }
      half4_t v4 = *(const half4_t*)(pp + 192);
      #pragma unroll
      for (int j = 0; j < 4; j++) P_lds[(192+j)*PLDSROWS + tid] = v4[j];
    }
  }
  int eBase = (r < 4) ? r*25 : 100 + (r-4)*24;
  int eCnt  = (r < 4) ? 25 : 24;

  for (int t = 0; t < 64; ++t) {
    // ---------------- P1 ----------------
    if (tid < 64)
      *(half8_t*)(hl + tid*8) = *(const half8_t*)(hbuf + b*512 + tid*8);
    __syncthreads();
    // gate partial: Xg + Whh[grow].h  (kept in register across barriers)
    float gacc = Xg[((size_t)t*32 + b)*2048 + grow];
    {
      const half8_t* wr = (const half8_t*)(Whh_h + (size_t)grow*512);
      const half8_t* hh = (const half8_t*)hl;
      for (int k8 = 0; k8 < 64; k8++) {
        half8_t w8 = wr[k8]; half8_t h8 = hh[k8];
        const half2_t* wp = (const half2_t*)&w8;
        const half2_t* hp = (const half2_t*)&h8;
        gacc = fdot2f(wp[0], hp[0], gacc);
        gacc = fdot2f(wp[1], hp[1], gacc);
        gacc = fdot2f(wp[2], hp[2], gacc);
        gacc = fdot2f(wp[3], hp[3], gacc);
      }
    }
    // hW slice: dims [r*64, r*64+64), 4 threads per dim
    {
      int dloc = tid >> 2, s = tid & 3;
      const half8_t* wr = (const half8_t*)(Wdec_h + (size_t)(r*64 + dloc)*512 + s*128);
      const half8_t* hh = (const half8_t*)(hl + s*128);
      float a = 0.f;
      for (int k8 = 0; k8 < 16; k8++) {
        half8_t w8 = wr[k8]; half8_t h8 = hh[k8];
        const half2_t* wp = (const half2_t*)&w8;
        const half2_t* hp = (const half2_t*)&h8;
        a = fdot2f(wp[0], hp[0], a);
        a = fdot2f(wp[1], hp[1], a);
        a = fdot2f(wp[2], hp[2], a);
        a = fdot2f(wp[3], hp[3], a);
      }
      redA[tid] = a;
    }
    __syncthreads();
    if (tid < 64)
      hw_g[b*512 + r*64 + tid] = redA[tid*4] + redA[tid*4+1] + redA[tid*4+2] + redA[tid*4+3];
    group_barrier(gbar);   // bar1: hw_g ready

    // ---------------- P2: e rows [eBase, eBase+eCnt) ----------------
    for (int i = tid; i < 512; i += 256) hwl[i] = hw_g[b*512 + i];
    __syncthreads();
    {
      int s = tid >> 5, nloc = tid & 31;       // lanes share s -> LDS broadcast reads
      if (nloc < eCnt) {
        int n = eBase + nloc;
        const half8_t* fp8 = (const half8_t*)(fproj_h + ((size_t)b*196 + n)*512 + s*64);
        float a = 0.f;
        for (int k8 = 0; k8 < 8; k8++) {
          half8_t f = fp8[k8];
          #pragma unroll
          for (int j = 0; j < 8; j++) {
            int k = s*64 + k8*8 + j;
            a += vl[k] * fast_tanh((float)f[j] + hwl[k]);
          }
        }
        ep[nloc][s] = a;
      }
    }
    __syncthreads();
    if (tid < eCnt) {
      float e = 0.f;
      #pragma unroll
      for (int s = 0; s < 8; s++) e += ep[tid][s];
      e_g[b*256 + eBase + tid] = e;
    }
    group_barrier(gbar);   // bar2: e ready

    // ---------------- P3: softmax (replicated) + gates + pointwise ----------------
    float ee = (tid < 196) ? e_g[b*256 + tid] : -1e30f;
    redA[tid] = ee;
    __syncthreads();
    for (int s = 128; s > 0; s >>= 1) {
      if (tid < s) redA[tid] = fmaxf(redA[tid], redA[tid+s]);
      __syncthreads();
    }
    float mx = redA[0];
    __syncthreads();
    float ex = (tid < 196) ? __expf(ee - mx) : 0.f;
    redA[tid] = ex;
    __syncthreads();
    for (int s = 128; s > 0; s >>= 1) {
      if (tid < s) redA[tid] += redA[tid+s];
      __syncthreads();
    }
    float al = ex * (1.f / redA[0]);
    sa[tid] = al;
    if (r == 0 && tid < 196)
      out_alpha[((size_t)b*64 + t)*196 + tid] = al;
    __syncthreads();
    // gates: gacc + sum_n alpha[n] * P[b][n][grow]
    if (tid < PLDSROWS) {
      for (int n = 0; n < 196; n++)
        gacc += sa[n] * (float)P_lds[n*PLDSROWS + tid];
    } else {
      const _Float16* pp = P_T + ((size_t)b*2048 + grow)*PTLD;
      for (int k8 = 0; k8 < 24; k8++) {
        half8_t v8 = *(const half8_t*)(pp + k8*8);
        #pragma unroll
        for (int j = 0; j < 8; j++) gacc += sa[k8*8+j] * (float)v8[j];
      }
      half4_t v4 = *(const half4_t*)(pp + 192);
      #pragma unroll
      for (int j = 0; j < 4; j++) gacc += sa[192+j] * (float)v4[j];
    }
    sm_g[tid] = gacc;
    __syncthreads();
    if (tid < 64) {
      float ig = sm_g[tid], fg = sm_g[64+tid], gg = sm_g[128+tid], og = sm_g[192+tid];
      float cn = fast_sig(fg)*c_reg + fast_sig(ig)*fast_tanh(gg);
      float hn = fast_sig(og)*fast_tanh(cn);
      c_reg = cn;
      _Float16 hh = (_Float16)hn;
      hbuf[b*512 + r*64 + tid] = hh;
      H_h[((size_t)t*32 + b)*512 + r*64 + tid] = hh;
    }
    group_barrier(gbar);   // bar3: h ready for next step
  }
}

// ---- logits: out[b][t][:] = H[t*32+b] @ Wfc^T + bfc ----
// Persistent-N: each block owns a 128-col stripe of Wfc, loops over all m-tiles.
__global__ void __launch_bounds__(512) logits_k(const _Float16* __restrict__ A,
    const _Float16* __restrict__ Bw, float* __restrict__ C,
    const float* __restrict__ bias) {
  int wave = threadIdx.x >> 6, lane = threadIdx.x & 63;
  int lr = lane & 15, quad = lane >> 4;
  int waveM = wave >> 1, waveN = wave & 1;
  int n0 = blockIdx.x*128 + waveN*64;
  const _Float16* Bp = Bw + (size_t)(n0 + lr)*512 + quad*8;
  float bv[4];
  #pragma unroll
  for (int ni = 0; ni < 4; ni++) bv[ni] = bias[n0 + ni*16 + lr];
  for (int it = 0; it < 8; ++it) {
    int m0 = (it*4 + waveM)*64;
    const _Float16* Ap = A + (size_t)(m0 + lr)*512 + quad*8;
    float4_t acc[4][4];
    #pragma unroll
    for (int i = 0; i < 4; i++)
      #pragma unroll
      for (int j = 0; j < 4; j++)
        acc[i][j] = (float4_t){0.f, 0.f, 0.f, 0.f};
    for (int k0 = 0; k0 < 512; k0 += 32) {
      half8_t af[4], bf[4];
      #pragma unroll
      for (int i = 0; i < 4; i++) af[i] = *(const half8_t*)(Ap + (size_t)i*16*512 + k0);
      #pragma unroll
      for (int i = 0; i < 4; i++) bf[i] = *(const half8_t*)(Bp + (size_t)i*16*512 + k0);
      #pragma unroll
      for (int mi = 0; mi < 4; mi++)
        #pragma unroll
        for (int ni = 0; ni < 4; ni++)
          acc[mi][ni] = __builtin_amdgcn_mfma_f32_16x16x32_f16(af[mi], bf[ni], acc[mi][ni], 0, 0, 0);
    }
    #pragma unroll
    for (int mi = 0; mi < 4; mi++) {
      #pragma unroll
      for (int ni = 0; ni < 4; ni++) {
        int col = n0 + ni*16 + lr;
        #pragma unroll
        for (int r = 0; r < 4; r++) {
          int row = m0 + mi*16 + quad*4 + r;
          size_t orow = (size_t)((row & 31)*64 + (row >> 5));
          __builtin_nontemporal_store(acc[mi][ni][r] + bv[ni], C + orow*32000 + col);
        }
      }
    }
  }
}

extern "C" void kernel_launch(void* const* d_in, const int* in_sizes, int n_in,
                              void* d_out, int out_size, void* d_ws, size_t ws_size,
                              hipStream_t stream) {
  const float* imgf  = (const float*)d_in[0];
  const int*   cap   = (const int*)d_in[1];
  const float* emb   = (const float*)d_in[2];
  const float* Wh0   = (const float*)d_in[3];
  const float* bh0   = (const float*)d_in[4];
  const float* Wc0   = (const float*)d_in[5];
  const float* bc0   = (const float*)d_in[6];
  const float* Wenc  = (const float*)d_in[7];
  const float* Wdec  = (const float*)d_in[8];
  const float* v_att = (const float*)d_in[9];
  const float* W_ih  = (const float*)d_in[10];
  const float* b_ih  = (const float*)d_in[11];
  const float* W_hh  = (const float*)d_in[12];
  const float* b_hh  = (const float*)d_in[13];
  const float* Wfc   = (const float*)d_in[14];
  const float* bfc   = (const float*)d_in[15];
  float* out = (float*)d_out;
  (void)in_sizes; (void)n_in; (void)out_size; (void)ws_size;

  char* ws = (char*)d_ws;
  size_t off = 0;
  auto alloc = [&](size_t bytes) -> void* {
    void* p = ws + off;
    off += (bytes + 255) & ~(size_t)255;
    return p;
  };
  _Float16* Wenc_h  = (_Float16*)alloc((size_t)512*512*2);
  _Float16* Wdec_h  = (_Float16*)alloc((size_t)512*512*2);
  _Float16* Wih_h   = (_Float16*)alloc((size_t)2048*1024*2);
  _Float16* Whh_h   = (_Float16*)alloc((size_t)2048*512*2);
  _Float16* Wfc_h   = (_Float16*)alloc((size_t)32000*512*2);
  _Float16* imgf_h  = (_Float16*)alloc((size_t)32*196*512*2);
  _Float16* fproj_h = (_Float16*)alloc((size_t)32*196*512*2);
  _Float16* P_T     = (_Float16*)alloc((size_t)32*2048*PTLD*2);
  _Float16* X_h     = (_Float16*)alloc((size_t)64*32*512*2);
  float*    Xg      = (float*)alloc((size_t)64*32*2048*4);
  float*    bsum    = (float*)alloc((size_t)2048*4);
  float*    c_state = (float*)alloc((size_t)32*512*4);
  _Float16* hbuf    = (_Float16*)alloc((size_t)32*512*2);
  float*    hw_g    = (float*)alloc((size_t)32*512*4);
  float*    e_g     = (float*)alloc((size_t)32*256*4);
  _Float16* H_h     = (_Float16*)alloc((size_t)2048*512*2);
  unsigned* bar     = (unsigned*)alloc((size_t)4096);

  auto cvt = [&](const float* s, _Float16* d, int n) {
    cvt_k<<<dim3((n/4 + 255)/256), dim3(256), 0, stream>>>(s, d, n);
  };
  cvt(Wenc, Wenc_h, 512*512);
  cvt(Wdec, Wdec_h, 512*512);
  cvt(W_ih, Wih_h, 2048*1024);
  cvt(W_hh, Whh_h, 2048*512);
  cvt(Wfc,  Wfc_h, 32000*512);
  cvt(imgf, imgf_h, 32*196*512);
  bias_sum_k<<<dim3(8), dim3(256), 0, stream>>>(b_ih, b_hh, bsum, bar);
  gather_emb_k<<<dim3(2048), dim3(256), 0, stream>>>(emb, cap, X_h);
  init_state_k<<<dim3(32), dim3(256), 0, stream>>>(imgf, Wh0, bh0, Wc0, bc0, c_state, hbuf);
  // feat_proj = image_features @ Wenc^T  -> fp16 [32*196, 512]
  gemm_abt_k<1><<<dim3(4, 49), dim3(256), 0, stream>>>(imgf_h, 512, Wenc_h, 512, fproj_h, 512, nullptr, 512);
  // P_T[b] = W_ih[:,512:] @ imgf[b]^T  -> fp16 [32][2048][PTLD]
  gemm_pt_k<<<dim3(2, 16, 32), dim3(256), 0, stream>>>(Wih_h + 512, imgf_h, P_T);
  // Xg = emb_x @ W_ih[:, :512]^T + (b_ih + b_hh)  -> fp32 [2048, 2048]
  gemm_abt_k<0><<<dim3(16, 16), dim3(256), 0, stream>>>(X_h, 512, Wih_h, 1024, Xg, 2048, bsum, 512);

  float* out_alpha = out + (size_t)32*64*32000;
  // all 64 recurrence steps in one persistent launch (32 groups x 8 blocks)
  loop_k<<<dim3(256), dim3(256), 0, stream>>>(Wdec_h, Whh_h, fproj_h, P_T, Xg,
      v_att, c_state, hbuf, hw_g, e_g, H_h, out_alpha, bar);
  // outputs = H @ Wfc^T + bfc (remapped rows)
  logits_k<<<dim3(250), dim3(512), 0, stream>>>(H_h, Wfc_h, out, bfc);
}

// Round 3
// 3226.606 us; speedup vs baseline: 4.0215x; 4.0215x over previous
//
#include <hip/hip_runtime.h>
#include <cstdint>
#include <cstddef>

typedef _Float16 half2_t __attribute__((ext_vector_type(2)));
typedef _Float16 half4_t __attribute__((ext_vector_type(4)));
typedef _Float16 half8_t __attribute__((ext_vector_type(8)));
typedef float    float4_t __attribute__((ext_vector_type(4)));

#define CAPLEN 65
#define PLDSROWS 192   // P rows pinned in LDS per block (gate types i,f,g; o streams)
#define PTLD 200       // P_T row stride in halfs (196 used, 400B, 16B-aligned)

#define AT_LD(p)     __hip_atomic_load((p), __ATOMIC_RELAXED, __HIP_MEMORY_SCOPE_AGENT)
#define AT_ST(p, v)  __hip_atomic_store((p), (v), __ATOMIC_RELAXED, __HIP_MEMORY_SCOPE_AGENT)

#if defined(__has_builtin)
#if __has_builtin(__builtin_amdgcn_fdot2)
#define HAS_FDOT2 1
#endif
#endif

__device__ __forceinline__ float fdot2f(half2_t a, half2_t b, float c) {
#ifdef HAS_FDOT2
  return __builtin_amdgcn_fdot2(a, b, c, false);
#else
  return c + (float)a[0]*(float)b[0] + (float)a[1]*(float)b[1];
#endif
}

__device__ __forceinline__ float fast_tanh(float x) {
  float e = __expf(2.f*x);
  return 1.f - 2.f/(e + 1.f);
}
__device__ __forceinline__ float fast_sig(float x) {
  return 1.f/(1.f + __expf(-x));
}

// ---------- fp32 -> fp16 convert (n % 4 == 0) ----------
__global__ void cvt_k(const float* __restrict__ s, _Float16* __restrict__ d, int n) {
  int i = (blockIdx.x*blockDim.x + threadIdx.x)*4;
  if (i < n) {
    float4 v = *(const float4*)(s + i);
    half4_t h;
    h[0] = (_Float16)v.x; h[1] = (_Float16)v.y; h[2] = (_Float16)v.z; h[3] = (_Float16)v.w;
    *(half4_t*)(d + i) = h;
  }
}

// bias sum + zero the group-barrier state (32 groups x 32 uints)
__global__ void bias_sum_k(const float* __restrict__ a, const float* __restrict__ b,
                           float* __restrict__ o, unsigned* __restrict__ bar) {
  int i = blockIdx.x*blockDim.x + threadIdx.x;
  if (i < 2048) o[i] = a[i] + b[i];
  if (i < 1024) bar[i] = 0u;
}

// gather embeddings for all (t,b): row r = t*32 + b, token = captions[b][t]
__global__ void gather_emb_k(const float* __restrict__ emb, const int* __restrict__ cap,
                             _Float16* __restrict__ X) {
  int r = blockIdx.x;
  int t = r >> 5, b = r & 31;
  int tok = cap[b*CAPLEN + t];
  const float* s = emb + (size_t)tok*512;
  _Float16* d = X + (size_t)r*512;
  for (int k = threadIdx.x; k < 512; k += blockDim.x) d[k] = (_Float16)s[k];
}

// feat_mean -> h0 (fp32, published), c0 (fp32); one wg per batch element
__global__ void init_state_k(const float* __restrict__ imgf,
                             const float* __restrict__ Wh0, const float* __restrict__ bh0,
                             const float* __restrict__ Wc0, const float* __restrict__ bc0,
                             float* __restrict__ c_state, float* __restrict__ hpubf) {
  __shared__ float fm[512];
  int b = blockIdx.x, tid = threadIdx.x;
  for (int dI = tid; dI < 512; dI += blockDim.x) {
    float s = 0.f;
    const float* p = imgf + ((size_t)b*196)*512 + dI;
    for (int n = 0; n < 196; n++) s += p[(size_t)n*512];
    fm[dI] = s * (1.f/196.f);
  }
  __syncthreads();
  for (int dI = tid; dI < 512; dI += blockDim.x) {
    const float* wh = Wh0 + (size_t)dI*512;
    const float* wc = Wc0 + (size_t)dI*512;
    float h = bh0[dI], c = bc0[dI];
    for (int k = 0; k < 512; k++) { h += fm[k]*wh[k]; c += fm[k]*wc[k]; }
    hpubf[b*512 + dI] = h;
    c_state[b*512 + dI] = c;
  }
}

// Generic C = A * B^T (+bias), fp16 in, fp32 acc, MFMA 16x16x32.
// MODE 0: fp32 C (+bias). MODE 1: fp16 C.
template<int MODE>
__global__ void __launch_bounds__(256) gemm_abt_k(const _Float16* __restrict__ A, int lda,
    const _Float16* __restrict__ B, int ldb, void* __restrict__ Cp, int ldc,
    const float* __restrict__ bias, int K) {
  int wave = threadIdx.x >> 6, lane = threadIdx.x & 63;
  int m0 = blockIdx.y*128 + (wave >> 1)*64;
  int n0 = blockIdx.x*128 + (wave & 1)*64;
  int lr = lane & 15, quad = lane >> 4;
  float4_t acc[4][4];
  #pragma unroll
  for (int i = 0; i < 4; i++)
    #pragma unroll
    for (int j = 0; j < 4; j++)
      acc[i][j] = (float4_t){0.f, 0.f, 0.f, 0.f};
  const _Float16* Ap = A + (size_t)(m0 + lr)*lda + quad*8;
  const _Float16* Bp = B + (size_t)(n0 + lr)*ldb + quad*8;
  for (int k0 = 0; k0 < K; k0 += 32) {
    half8_t af[4], bf[4];
    #pragma unroll
    for (int i = 0; i < 4; i++) af[i] = *(const half8_t*)(Ap + (size_t)i*16*lda + k0);
    #pragma unroll
    for (int i = 0; i < 4; i++) bf[i] = *(const half8_t*)(Bp + (size_t)i*16*ldb + k0);
    #pragma unroll
    for (int mi = 0; mi < 4; mi++)
      #pragma unroll
      for (int ni = 0; ni < 4; ni++)
        acc[mi][ni] = __builtin_amdgcn_mfma_f32_16x16x32_f16(af[mi], bf[ni], acc[mi][ni], 0, 0, 0);
  }
  #pragma unroll
  for (int mi = 0; mi < 4; mi++) {
    #pragma unroll
    for (int ni = 0; ni < 4; ni++) {
      int col = n0 + ni*16 + lr;
      float bv = (MODE == 1) ? 0.f : bias[col];
      #pragma unroll
      for (int r = 0; r < 4; r++) {
        int row = m0 + mi*16 + quad*4 + r;
        if (MODE == 1) {
          ((_Float16*)Cp)[(size_t)row*ldc + col] = (_Float16)acc[mi][ni][r];
        } else {
          ((float*)Cp)[(size_t)row*ldc + col] = acc[mi][ni][r] + bv;
        }
      }
    }
  }
}

// P_T[b][row][n] = sum_k W_ih[row][512+k] * imgf[b][n][k]   (fp16 out, ldc=PTLD)
// grid (2, 16, 32): x = n-tile(128), y = m-tile(128), z = b
__global__ void __launch_bounds__(256) gemm_pt_k(const _Float16* __restrict__ A,
    const _Float16* __restrict__ Bimg, _Float16* __restrict__ Cpt) {
  int z = blockIdx.z;
  const _Float16* B = Bimg + (size_t)z*196*512;   // rows >=196 read OOB garbage; cols masked downstream
  _Float16* C = Cpt + (size_t)z*2048*PTLD;
  int wave = threadIdx.x >> 6, lane = threadIdx.x & 63;
  int m0 = blockIdx.y*128 + (wave >> 1)*64;
  int n0 = blockIdx.x*128 + (wave & 1)*64;
  int lr = lane & 15, quad = lane >> 4;
  float4_t acc[4][4];
  #pragma unroll
  for (int i = 0; i < 4; i++)
    #pragma unroll
    for (int j = 0; j < 4; j++)
      acc[i][j] = (float4_t){0.f, 0.f, 0.f, 0.f};
  const _Float16* Ap = A + (size_t)(m0 + lr)*1024 + quad*8;
  const _Float16* Bp = B + (size_t)(n0 + lr)*512 + quad*8;
  for (int k0 = 0; k0 < 512; k0 += 32) {
    half8_t af[4], bf[4];
    #pragma unroll
    for (int i = 0; i < 4; i++) af[i] = *(const half8_t*)(Ap + (size_t)i*16*1024 + k0);
    #pragma unroll
    for (int i = 0; i < 4; i++) bf[i] = *(const half8_t*)(Bp + (size_t)i*16*512 + k0);
    #pragma unroll
    for (int mi = 0; mi < 4; mi++)
      #pragma unroll
      for (int ni = 0; ni < 4; ni++)
        acc[mi][ni] = __builtin_amdgcn_mfma_f32_16x16x32_f16(af[mi], bf[ni], acc[mi][ni], 0, 0, 0);
  }
  #pragma unroll
  for (int mi = 0; mi < 4; mi++) {
    #pragma unroll
    for (int ni = 0; ni < 4; ni++) {
      int col = n0 + ni*16 + lr;
      if (col < PTLD) {
        #pragma unroll
        for (int r = 0; r < 4; r++) {
          int row = m0 + mi*16 + quad*4 + r;
          C[(size_t)row*PTLD + col] = (_Float16)acc[mi][ni][r];
        }
      }
    }
  }
}

// ---- 8-block group barrier, NO acquire fences (L2 stays hot) ----
// Spin: RELAXED (device-coherent at L3; proven to observe remote updates in r1/r2).
// Arrive: RELEASE (waitcnt + dirty-line writeback only; does NOT evict clean lines).
// All cross-block payload goes through relaxed agent atomics (bypass stale L1/L2).
__device__ __forceinline__ void group_barrier(unsigned* __restrict__ gb) {
  __syncthreads();   // compiler emits s_waitcnt vmcnt(0) before s_barrier: stores drained
  if (threadIdx.x == 0) {
    unsigned sense = AT_LD(gb + 1);
    unsigned a = __hip_atomic_fetch_add(gb, 1u, __ATOMIC_RELEASE, __HIP_MEMORY_SCOPE_AGENT) + 1u;
    if (a == 8u) {
      AT_ST(gb, 0u);
      // RELEASE flip: orders the counter reset before the sense change
      __hip_atomic_store(gb + 1, sense + 1u, __ATOMIC_RELEASE, __HIP_MEMORY_SCOPE_AGENT);
    } else {
      while (AT_LD(gb + 1) == sense)
        __builtin_amdgcn_s_sleep(1);
    }
  }
  __syncthreads();
}

// ---- persistent recurrence: 32 independent groups of 8 blocks (one group per b) ----
// block: b = bid&31, r = bid>>5. 1 block/CU (big LDS). Per step:
//   P1: gacc = Xg + Whh.h (reg), hW slice -> hw_g(atomic) | bar |
//   P2: e rows -> e_g(atomic) | bar |
//   P3: softmax (replicated) + gates (alpha.P from LDS/L2) + pointwise, h->hpubf(atomic) | bar
__global__ void __launch_bounds__(256) loop_k(
    const _Float16* __restrict__ Wdec_h,   // [512][512]
    const _Float16* __restrict__ Whh_h,    // [2048][512]
    const _Float16* __restrict__ fproj_h,  // [32][196][512]
    const _Float16* __restrict__ P_T,      // [32][2048][PTLD]
    const float*    __restrict__ Xg,       // [64*32][2048]
    const float*    __restrict__ v_att,    // [512]
    const float*    __restrict__ c_init,   // [32][512]
    float*          __restrict__ hpubf,    // [32][512] fp32 published h (atomic access)
    float*          __restrict__ hw_g,     // [32][512] (atomic access)
    float*          __restrict__ e_g,      // [32][256] (atomic access)
    _Float16*       __restrict__ H_h,      // [64*32][512]
    float*          __restrict__ out_alpha,// [32][64][196]
    unsigned*       __restrict__ bar) {
  __shared__ _Float16 P_lds[196*PLDSROWS]; // [n][tid], rows tid<PLDSROWS
  __shared__ _Float16 hl[512];
  __shared__ float vl[512];
  __shared__ float hwl[512];
  __shared__ float redA[256];
  __shared__ float sa[256];
  __shared__ float ep[32][9];
  __shared__ float sm_g[256];
  int bid = blockIdx.x, tid = threadIdx.x;
  int b = bid & 31, r = bid >> 5;
  unsigned* gbar = bar + b*32;
  int typ = tid >> 6, dl = tid & 63;
  int grow = typ*512 + r*64 + dl;          // this thread's gate row

  for (int i = tid; i < 512; i += 256) vl[i] = v_att[i];
  float c_reg = (tid < 64) ? c_init[b*512 + r*64 + tid] : 0.f;

  // stage pinned P rows into LDS (once): P_lds[n][tid] = P_T[b][grow][n]
  {
    const _Float16* pp = P_T + ((size_t)b*2048 + grow)*PTLD;
    if (tid < PLDSROWS) {
      for (int k8 = 0; k8 < 24; k8++) {
        half8_t v8 = *(const half8_t*)(pp + k8*8);
        #pragma unroll
        for (int j = 0; j < 8; j++) P_lds[(k8*8+j)*PLDSROWS + tid] = v8[j];
      }
      half4_t v4 = *(const half4_t*)(pp + 192);
      #pragma unroll
      for (int j = 0; j < 4; j++) P_lds[(192+j)*PLDSROWS + tid] = v4[j];
    }
  }
  int eBase = (r < 4) ? r*25 : 100 + (r-4)*24;
  int eCnt  = (r < 4) ? 25 : 24;

  for (int t = 0; t < 64; ++t) {
    // ---------------- P1 ----------------
    // pull published h (fp32, device-coherent) -> fp16 LDS
    for (int i = tid; i < 512; i += 256)
      hl[i] = (_Float16)AT_LD(hpubf + b*512 + i);
    __syncthreads();
    // gate partial: Xg + Whh[grow].h  (kept in register across barriers)
    float gacc = Xg[((size_t)t*32 + b)*2048 + grow];
    {
      const half8_t* wr = (const half8_t*)(Whh_h + (size_t)grow*512);
      const half8_t* hh = (const half8_t*)hl;
      for (int k8 = 0; k8 < 64; k8++) {
        half8_t w8 = wr[k8]; half8_t h8 = hh[k8];
        const half2_t* wp = (const half2_t*)&w8;
        const half2_t* hp = (const half2_t*)&h8;
        gacc = fdot2f(wp[0], hp[0], gacc);
        gacc = fdot2f(wp[1], hp[1], gacc);
        gacc = fdot2f(wp[2], hp[2], gacc);
        gacc = fdot2f(wp[3], hp[3], gacc);
      }
    }
    // hW slice: dims [r*64, r*64+64), 4 threads per dim
    {
      int dloc = tid >> 2, s = tid & 3;
      const half8_t* wr = (const half8_t*)(Wdec_h + (size_t)(r*64 + dloc)*512 + s*128);
      const half8_t* hh = (const half8_t*)(hl + s*128);
      float a = 0.f;
      for (int k8 = 0; k8 < 16; k8++) {
        half8_t w8 = wr[k8]; half8_t h8 = hh[k8];
        const half2_t* wp = (const half2_t*)&w8;
        const half2_t* hp = (const half2_t*)&h8;
        a = fdot2f(wp[0], hp[0], a);
        a = fdot2f(wp[1], hp[1], a);
        a = fdot2f(wp[2], hp[2], a);
        a = fdot2f(wp[3], hp[3], a);
      }
      redA[tid] = a;
    }
    __syncthreads();
    if (tid < 64)
      AT_ST(hw_g + b*512 + r*64 + tid,
            redA[tid*4] + redA[tid*4+1] + redA[tid*4+2] + redA[tid*4+3]);
    group_barrier(gbar);   // bar1: hw_g ready

    // ---------------- P2: e rows [eBase, eBase+eCnt) ----------------
    for (int i = tid; i < 512; i += 256) hwl[i] = AT_LD(hw_g + b*512 + i);
    __syncthreads();
    {
      int s = tid >> 5, nloc = tid & 31;       // lanes share s -> LDS broadcast reads
      if (nloc < eCnt) {
        int n = eBase + nloc;
        const half8_t* fp8 = (const half8_t*)(fproj_h + ((size_t)b*196 + n)*512 + s*64);
        float a = 0.f;
        for (int k8 = 0; k8 < 8; k8++) {
          half8_t f = fp8[k8];
          #pragma unroll
          for (int j = 0; j < 8; j++) {
            int k = s*64 + k8*8 + j;
            a += vl[k] * fast_tanh((float)f[j] + hwl[k]);
          }
        }
        ep[nloc][s] = a;
      }
    }
    __syncthreads();
    if (tid < eCnt) {
      float e = 0.f;
      #pragma unroll
      for (int s = 0; s < 8; s++) e += ep[tid][s];
      AT_ST(e_g + b*256 + eBase + tid, e);
    }
    group_barrier(gbar);   // bar2: e ready

    // ---------------- P3: softmax (replicated) + gates + pointwise ----------------
    float ee = (tid < 196) ? AT_LD(e_g + b*256 + tid) : -1e30f;
    redA[tid] = ee;
    __syncthreads();
    for (int s = 128; s > 0; s >>= 1) {
      if (tid < s) redA[tid] = fmaxf(redA[tid], redA[tid+s]);
      __syncthreads();
    }
    float mx = redA[0];
    __syncthreads();
    float ex = (tid < 196) ? __expf(ee - mx) : 0.f;
    redA[tid] = ex;
    __syncthreads();
    for (int s = 128; s > 0; s >>= 1) {
      if (tid < s) redA[tid] += redA[tid+s];
      __syncthreads();
    }
    float al = ex * (1.f / redA[0]);
    sa[tid] = al;
    if (r == 0 && tid < 196)
      out_alpha[((size_t)b*64 + t)*196 + tid] = al;
    __syncthreads();
    // gates: gacc + sum_n alpha[n] * P[b][n][grow]
    if (tid < PLDSROWS) {
      for (int n = 0; n < 196; n++)
        gacc += sa[n] * (float)P_lds[n*PLDSROWS + tid];
    } else {
      const _Float16* pp = P_T + ((size_t)b*2048 + grow)*PTLD;
      for (int k8 = 0; k8 < 24; k8++) {
        half8_t v8 = *(const half8_t*)(pp + k8*8);
        #pragma unroll
        for (int j = 0; j < 8; j++) gacc += sa[k8*8+j] * (float)v8[j];
      }
      half4_t v4 = *(const half4_t*)(pp + 192);
      #pragma unroll
      for (int j = 0; j < 4; j++) gacc += sa[192+j] * (float)v4[j];
    }
    sm_g[tid] = gacc;
    __syncthreads();
    if (tid < 64) {
      float ig = sm_g[tid], fg = sm_g[64+tid], gg = sm_g[128+tid], og = sm_g[192+tid];
      float cn = fast_sig(fg)*c_reg + fast_sig(ig)*fast_tanh(gg);
      float hn = fast_sig(og)*fast_tanh(cn);
      c_reg = cn;
      AT_ST(hpubf + b*512 + r*64 + tid, hn);
      H_h[((size_t)t*32 + b)*512 + r*64 + tid] = (_Float16)hn;
    }
    group_barrier(gbar);   // bar3: h ready for next step
  }
}

// ---- logits: out[b][t][:] = H[t*32+b] @ Wfc^T + bfc ----
// Persistent-N: each block owns a 128-col stripe of Wfc, loops over all m-tiles.
__global__ void __launch_bounds__(512) logits_k(const _Float16* __restrict__ A,
    const _Float16* __restrict__ Bw, float* __restrict__ C,
    const float* __restrict__ bias) {
  int wave = threadIdx.x >> 6, lane = threadIdx.x & 63;
  int lr = lane & 15, quad = lane >> 4;
  int waveM = wave >> 1, waveN = wave & 1;
  int n0 = blockIdx.x*128 + waveN*64;
  const _Float16* Bp = Bw + (size_t)(n0 + lr)*512 + quad*8;
  float bv[4];
  #pragma unroll
  for (int ni = 0; ni < 4; ni++) bv[ni] = bias[n0 + ni*16 + lr];
  for (int it = 0; it < 8; ++it) {
    int m0 = (it*4 + waveM)*64;
    const _Float16* Ap = A + (size_t)(m0 + lr)*512 + quad*8;
    float4_t acc[4][4];
    #pragma unroll
    for (int i = 0; i < 4; i++)
      #pragma unroll
      for (int j = 0; j < 4; j++)
        acc[i][j] = (float4_t){0.f, 0.f, 0.f, 0.f};
    for (int k0 = 0; k0 < 512; k0 += 32) {
      half8_t af[4], bf[4];
      #pragma unroll
      for (int i = 0; i < 4; i++) af[i] = *(const half8_t*)(Ap + (size_t)i*16*512 + k0);
      #pragma unroll
      for (int i = 0; i < 4; i++) bf[i] = *(const half8_t*)(Bp + (size_t)i*16*512 + k0);
      #pragma unroll
      for (int mi = 0; mi < 4; mi++)
        #pragma unroll
        for (int ni = 0; ni < 4; ni++)
          acc[mi][ni] = __builtin_amdgcn_mfma_f32_16x16x32_f16(af[mi], bf[ni], acc[mi][ni], 0, 0, 0);
    }
    #pragma unroll
    for (int mi = 0; mi < 4; mi++) {
      #pragma unroll
      for (int ni = 0; ni < 4; ni++) {
        int col = n0 + ni*16 + lr;
        #pragma unroll
        for (int r = 0; r < 4; r++) {
          int row = m0 + mi*16 + quad*4 + r;
          size_t orow = (size_t)((row & 31)*64 + (row >> 5));
          __builtin_nontemporal_store(acc[mi][ni][r] + bv[ni], C + orow*32000 + col);
        }
      }
    }
  }
}

extern "C" void kernel_launch(void* const* d_in, const int* in_sizes, int n_in,
                              void* d_out, int out_size, void* d_ws, size_t ws_size,
                              hipStream_t stream) {
  const float* imgf  = (const float*)d_in[0];
  const int*   cap   = (const int*)d_in[1];
  const float* emb   = (const float*)d_in[2];
  const float* Wh0   = (const float*)d_in[3];
  const float* bh0   = (const float*)d_in[4];
  const float* Wc0   = (const float*)d_in[5];
  const float* bc0   = (const float*)d_in[6];
  const float* Wenc  = (const float*)d_in[7];
  const float* Wdec  = (const float*)d_in[8];
  const float* v_att = (const float*)d_in[9];
  const float* W_ih  = (const float*)d_in[10];
  const float* b_ih  = (const float*)d_in[11];
  const float* W_hh  = (const float*)d_in[12];
  const float* b_hh  = (const float*)d_in[13];
  const float* Wfc   = (const float*)d_in[14];
  const float* bfc   = (const float*)d_in[15];
  float* out = (float*)d_out;
  (void)in_sizes; (void)n_in; (void)out_size; (void)ws_size;

  char* ws = (char*)d_ws;
  size_t off = 0;
  auto alloc = [&](size_t bytes) -> void* {
    void* p = ws + off;
    off += (bytes + 255) & ~(size_t)255;
    return p;
  };
  _Float16* Wenc_h  = (_Float16*)alloc((size_t)512*512*2);
  _Float16* Wdec_h  = (_Float16*)alloc((size_t)512*512*2);
  _Float16* Wih_h   = (_Float16*)alloc((size_t)2048*1024*2);
  _Float16* Whh_h   = (_Float16*)alloc((size_t)2048*512*2);
  _Float16* Wfc_h   = (_Float16*)alloc((size_t)32000*512*2);
  _Float16* imgf_h  = (_Float16*)alloc((size_t)32*196*512*2);
  _Float16* fproj_h = (_Float16*)alloc((size_t)32*196*512*2);
  _Float16* P_T     = (_Float16*)alloc((size_t)32*2048*PTLD*2);
  _Float16* X_h     = (_Float16*)alloc((size_t)64*32*512*2);
  float*    Xg      = (float*)alloc((size_t)64*32*2048*4);
  float*    bsum    = (float*)alloc((size_t)2048*4);
  float*    c_state = (float*)alloc((size_t)32*512*4);
  float*    hpubf   = (float*)alloc((size_t)32*512*4);
  float*    hw_g    = (float*)alloc((size_t)32*512*4);
  float*    e_g     = (float*)alloc((size_t)32*256*4);
  _Float16* H_h     = (_Float16*)alloc((size_t)2048*512*2);
  unsigned* bar     = (unsigned*)alloc((size_t)4096);

  auto cvt = [&](const float* s, _Float16* d, int n) {
    cvt_k<<<dim3((n/4 + 255)/256), dim3(256), 0, stream>>>(s, d, n);
  };
  cvt(Wenc, Wenc_h, 512*512);
  cvt(Wdec, Wdec_h, 512*512);
  cvt(W_ih, Wih_h, 2048*1024);
  cvt(W_hh, Whh_h, 2048*512);
  cvt(Wfc,  Wfc_h, 32000*512);
  cvt(imgf, imgf_h, 32*196*512);
  bias_sum_k<<<dim3(8), dim3(256), 0, stream>>>(b_ih, b_hh, bsum, bar);
  gather_emb_k<<<dim3(2048), dim3(256), 0, stream>>>(emb, cap, X_h);
  init_state_k<<<dim3(32), dim3(256), 0, stream>>>(imgf, Wh0, bh0, Wc0, bc0, c_state, hpubf);
  // feat_proj = image_features @ Wenc^T  -> fp16 [32*196, 512]
  gemm_abt_k<1><<<dim3(4, 49), dim3(256), 0, stream>>>(imgf_h, 512, Wenc_h, 512, fproj_h, 512, nullptr, 512);
  // P_T[b] = W_ih[:,512:] @ imgf[b]^T  -> fp16 [32][2048][PTLD]
  gemm_pt_k<<<dim3(2, 16, 32), dim3(256), 0, stream>>>(Wih_h + 512, imgf_h, P_T);
  // Xg = emb_x @ W_ih[:, :512]^T + (b_ih + b_hh)  -> fp32 [2048, 2048]
  gemm_abt_k<0><<<dim3(16, 16), dim3(256), 0, stream>>>(X_h, 512, Wih_h, 1024, Xg, 2048, bsum, 512);

  float* out_alpha = out + (size_t)32*64*32000;
  // all 64 recurrence steps in one persistent launch (32 groups x 8 blocks)
  loop_k<<<dim3(256), dim3(256), 0, stream>>>(Wdec_h, Whh_h, fproj_h, P_T, Xg,
      v_att, c_state, hpubf, hw_g, e_g, H_h, out_alpha, bar);
  // outputs = H @ Wfc^T + bfc (remapped rows)
  logits_k<<<dim3(250), dim3(512), 0, stream>>>(H_h, Wfc_h, out, bfc);
}

// Round 4
// 2900.429 us; speedup vs baseline: 4.4738x; 1.1125x over previous
//
#include <hip/hip_runtime.h>
#include <cstdint>
#include <cstddef>

typedef _Float16 half2_t __attribute__((ext_vector_type(2)));
typedef _Float16 half4_t __attribute__((ext_vector_type(4)));
typedef _Float16 half8_t __attribute__((ext_vector_type(8)));
typedef float    float4_t __attribute__((ext_vector_type(4)));

#define CAPLEN 65
#define PTLD 200       // P_T row stride in halfs (196 used, 400B, 16B-aligned)

#define AT_LD(p)     __hip_atomic_load((p), __ATOMIC_RELAXED, __HIP_MEMORY_SCOPE_AGENT)
#define AT_ST(p, v)  __hip_atomic_store((p), (v), __ATOMIC_RELAXED, __HIP_MEMORY_SCOPE_AGENT)

#if defined(__has_builtin)
#if __has_builtin(__builtin_amdgcn_fdot2)
#define HAS_FDOT2 1
#endif
#endif

__device__ __forceinline__ float fdot2f(half2_t a, half2_t b, float c) {
#ifdef HAS_FDOT2
  return __builtin_amdgcn_fdot2(a, b, c, false);
#else
  return c + (float)a[0]*(float)b[0] + (float)a[1]*(float)b[1];
#endif
}

__device__ __forceinline__ float fast_tanh(float x) {
  float e = __expf(2.f*x);
  return 1.f - 2.f/(e + 1.f);
}
__device__ __forceinline__ float fast_sig(float x) {
  return 1.f/(1.f + __expf(-x));
}

// ---------- fp32 -> fp16 convert (n % 4 == 0) ----------
__global__ void cvt_k(const float* __restrict__ s, _Float16* __restrict__ d, int n) {
  int i = (blockIdx.x*blockDim.x + threadIdx.x)*4;
  if (i < n) {
    float4 v = *(const float4*)(s + i);
    half4_t h;
    h[0] = (_Float16)v.x; h[1] = (_Float16)v.y; h[2] = (_Float16)v.z; h[3] = (_Float16)v.w;
    *(half4_t*)(d + i) = h;
  }
}

// bias sum + zero the group-barrier state (32 groups x 32 uints)
__global__ void bias_sum_k(const float* __restrict__ a, const float* __restrict__ b,
                           float* __restrict__ o, unsigned* __restrict__ bar) {
  int i = blockIdx.x*blockDim.x + threadIdx.x;
  if (i < 2048) o[i] = a[i] + b[i];
  if (i < 1024) bar[i] = 0u;
}

// gather embeddings for all (t,b): row r = t*32 + b, token = captions[b][t]
__global__ void gather_emb_k(const float* __restrict__ emb, const int* __restrict__ cap,
                             _Float16* __restrict__ X) {
  int r = blockIdx.x;
  int t = r >> 5, b = r & 31;
  int tok = cap[b*CAPLEN + t];
  const float* s = emb + (size_t)tok*512;
  _Float16* d = X + (size_t)r*512;
  for (int k = threadIdx.x; k < 512; k += blockDim.x) d[k] = (_Float16)s[k];
}

// feat_mean -> h0 (fp32, published), c0 (fp32); one wg per batch element
__global__ void init_state_k(const float* __restrict__ imgf,
                             const float* __restrict__ Wh0, const float* __restrict__ bh0,
                             const float* __restrict__ Wc0, const float* __restrict__ bc0,
                             float* __restrict__ c_state, float* __restrict__ hpubf) {
  __shared__ float fm[512];
  int b = blockIdx.x, tid = threadIdx.x;
  for (int dI = tid; dI < 512; dI += blockDim.x) {
    float s = 0.f;
    const float* p = imgf + ((size_t)b*196)*512 + dI;
    for (int n = 0; n < 196; n++) s += p[(size_t)n*512];
    fm[dI] = s * (1.f/196.f);
  }
  __syncthreads();
  for (int dI = tid; dI < 512; dI += blockDim.x) {
    const float* wh = Wh0 + (size_t)dI*512;
    const float* wc = Wc0 + (size_t)dI*512;
    float h = bh0[dI], c = bc0[dI];
    for (int k = 0; k < 512; k++) { h += fm[k]*wh[k]; c += fm[k]*wc[k]; }
    hpubf[b*512 + dI] = h;
    c_state[b*512 + dI] = c;
  }
}

// Generic C = A * B^T (+bias), fp16 in, fp32 acc, MFMA 16x16x32.
// MODE 0: fp32 C (+bias). MODE 1: fp16 C.
template<int MODE>
__global__ void __launch_bounds__(256) gemm_abt_k(const _Float16* __restrict__ A, int lda,
    const _Float16* __restrict__ B, int ldb, void* __restrict__ Cp, int ldc,
    const float* __restrict__ bias, int K) {
  int wave = threadIdx.x >> 6, lane = threadIdx.x & 63;
  int m0 = blockIdx.y*128 + (wave >> 1)*64;
  int n0 = blockIdx.x*128 + (wave & 1)*64;
  int lr = lane & 15, quad = lane >> 4;
  float4_t acc[4][4];
  #pragma unroll
  for (int i = 0; i < 4; i++)
    #pragma unroll
    for (int j = 0; j < 4; j++)
      acc[i][j] = (float4_t){0.f, 0.f, 0.f, 0.f};
  const _Float16* Ap = A + (size_t)(m0 + lr)*lda + quad*8;
  const _Float16* Bp = B + (size_t)(n0 + lr)*ldb + quad*8;
  for (int k0 = 0; k0 < K; k0 += 32) {
    half8_t af[4], bf[4];
    #pragma unroll
    for (int i = 0; i < 4; i++) af[i] = *(const half8_t*)(Ap + (size_t)i*16*lda + k0);
    #pragma unroll
    for (int i = 0; i < 4; i++) bf[i] = *(const half8_t*)(Bp + (size_t)i*16*ldb + k0);
    #pragma unroll
    for (int mi = 0; mi < 4; mi++)
      #pragma unroll
      for (int ni = 0; ni < 4; ni++)
        acc[mi][ni] = __builtin_amdgcn_mfma_f32_16x16x32_f16(af[mi], bf[ni], acc[mi][ni], 0, 0, 0);
  }
  #pragma unroll
  for (int mi = 0; mi < 4; mi++) {
    #pragma unroll
    for (int ni = 0; ni < 4; ni++) {
      int col = n0 + ni*16 + lr;
      float bv = (MODE == 1) ? 0.f : bias[col];
      #pragma unroll
      for (int r = 0; r < 4; r++) {
        int row = m0 + mi*16 + quad*4 + r;
        if (MODE == 1) {
          ((_Float16*)Cp)[(size_t)row*ldc + col] = (_Float16)acc[mi][ni][r];
        } else {
          ((float*)Cp)[(size_t)row*ldc + col] = acc[mi][ni][r] + bv;
        }
      }
    }
  }
}

// P_T[b][row][n] = sum_k W_ih[row][512+k] * imgf[b][n][k]   (fp16 out, ldc=PTLD)
// grid (2, 16, 32): x = n-tile(128), y = m-tile(128), z = b
__global__ void __launch_bounds__(256) gemm_pt_k(const _Float16* __restrict__ A,
    const _Float16* __restrict__ Bimg, _Float16* __restrict__ Cpt) {
  int z = blockIdx.z;
  const _Float16* B = Bimg + (size_t)z*196*512;   // rows >=196 read OOB garbage; cols masked downstream
  _Float16* C = Cpt + (size_t)z*2048*PTLD;
  int wave = threadIdx.x >> 6, lane = threadIdx.x & 63;
  int m0 = blockIdx.y*128 + (wave >> 1)*64;
  int n0 = blockIdx.x*128 + (wave & 1)*64;
  int lr = lane & 15, quad = lane >> 4;
  float4_t acc[4][4];
  #pragma unroll
  for (int i = 0; i < 4; i++)
    #pragma unroll
    for (int j = 0; j < 4; j++)
      acc[i][j] = (float4_t){0.f, 0.f, 0.f, 0.f};
  const _Float16* Ap = A + (size_t)(m0 + lr)*1024 + quad*8;
  const _Float16* Bp = B + (size_t)(n0 + lr)*512 + quad*8;
  for (int k0 = 0; k0 < 512; k0 += 32) {
    half8_t af[4], bf[4];
    #pragma unroll
    for (int i = 0; i < 4; i++) af[i] = *(const half8_t*)(Ap + (size_t)i*16*1024 + k0);
    #pragma unroll
    for (int i = 0; i < 4; i++) bf[i] = *(const half8_t*)(Bp + (size_t)i*16*512 + k0);
    #pragma unroll
    for (int mi = 0; mi < 4; mi++)
      #pragma unroll
      for (int ni = 0; ni < 4; ni++)
        acc[mi][ni] = __builtin_amdgcn_mfma_f32_16x16x32_f16(af[mi], bf[ni], acc[mi][ni], 0, 0, 0);
  }
  #pragma unroll
  for (int mi = 0; mi < 4; mi++) {
    #pragma unroll
    for (int ni = 0; ni < 4; ni++) {
      int col = n0 + ni*16 + lr;
      if (col < PTLD) {
        #pragma unroll
        for (int r = 0; r < 4; r++) {
          int row = m0 + mi*16 + quad*4 + r;
          C[(size_t)row*PTLD + col] = (_Float16)acc[mi][ni][r];
        }
      }
    }
  }
}

// ---- 8-block group barrier, NO acquire fences (L2 stays hot) ----
// Spin: RELAXED; arrive: RELEASE (writeback of dirty lines only, keeps clean
// weight lines resident). All cross-block payload uses relaxed agent atomics.
__device__ __forceinline__ void group_barrier(unsigned* __restrict__ gb) {
  __syncthreads();   // compiler drains vmcnt before s_barrier: stores done
  if (threadIdx.x == 0) {
    unsigned sense = AT_LD(gb + 1);
    unsigned a = __hip_atomic_fetch_add(gb, 1u, __ATOMIC_RELEASE, __HIP_MEMORY_SCOPE_AGENT) + 1u;
    if (a == 8u) {
      AT_ST(gb, 0u);
      __hip_atomic_store(gb + 1, sense + 1u, __ATOMIC_RELEASE, __HIP_MEMORY_SCOPE_AGENT);
    } else {
      while (AT_LD(gb + 1) == sense)
        __builtin_amdgcn_s_sleep(1);
    }
  }
  __syncthreads();
}

// ---- persistent recurrence: 32 groups (one per b) of 8 blocks (one per r-slice) ----
// r = bid & 7  -> all blocks sharing an r-slice (same Whh/Wdec rows) land on the
//                 SAME XCD under round-robin dispatch => slice stays L2-resident.
// b = bid >> 3 -> group spans 8 XCDs; barrier+payload via L3 relaxed atomics.
// Per step: P1: gacc = Xg + Whh.h (reg), hW slice -> hw_g | bar |
//           P2: e slice -> e_g | bar |
//           P3: softmax (replicated) + gates (alpha.P, all P in LDS) + pointwise | bar
__global__ void __launch_bounds__(256) loop_k(
    const _Float16* __restrict__ Wdec_h,   // [512][512]
    const _Float16* __restrict__ Whh_h,    // [2048][512]
    const _Float16* __restrict__ fproj_h,  // [32][196][512]
    const _Float16* __restrict__ P_T,      // [32][2048][PTLD]
    const float*    __restrict__ Xg,       // [64*32][2048]
    const float*    __restrict__ v_att,    // [512]
    const float*    __restrict__ c_init,   // [32][512]
    float*          __restrict__ hpubf,    // [32][512] fp32 published h (atomic access)
    float*          __restrict__ hw_g,     // [32][512] (atomic access)
    float*          __restrict__ e_g,      // [32][256] (atomic access)
    _Float16*       __restrict__ H_h,      // [64*32][512]
    float*          __restrict__ out_alpha,// [32][64][196]
    unsigned*       __restrict__ bar) {
  __shared__ _Float16 P_lds[98*256*2];     // [n2][row][2] half2-interleaved, 100352B
  __shared__ _Float16 hl[512];
  __shared__ float vl[512];
  __shared__ float hwl[512];
  __shared__ float redA[256];
  __shared__ float sa[256];
  __shared__ float ep[32][9];
  __shared__ float sm_g[256];
  int bid = blockIdx.x, tid = threadIdx.x;
  int r = bid & 7, b = bid >> 3;
  unsigned* gbar = bar + b*32;
  int typ = tid >> 6, dl = tid & 63;
  int grow = typ*512 + r*64 + dl;          // this thread's gate row

  for (int i = tid; i < 512; i += 256) vl[i] = v_att[i];
  float c_reg = (tid < 64) ? c_init[b*512 + r*64 + tid] : 0.f;

  // stage ALL 256 P rows into LDS (once): P_lds2[n2*256 + tid] = P_T[b][grow][2n2..2n2+1]
  {
    const _Float16* pp = P_T + ((size_t)b*2048 + grow)*PTLD;
    half2_t* P2 = (half2_t*)P_lds;
    for (int k8 = 0; k8 < 24; k8++) {
      half8_t v8 = *(const half8_t*)(pp + k8*8);
      #pragma unroll
      for (int j2 = 0; j2 < 4; j2++) {
        half2_t h2; h2[0] = v8[2*j2]; h2[1] = v8[2*j2+1];
        P2[(k8*4 + j2)*256 + tid] = h2;
      }
    }
    half4_t v4 = *(const half4_t*)(pp + 192);
    half2_t h2a; h2a[0] = v4[0]; h2a[1] = v4[1];
    half2_t h2b; h2b[0] = v4[2]; h2b[1] = v4[3];
    P2[96*256 + tid] = h2a;
    P2[97*256 + tid] = h2b;
  }
  int eBase = (r < 4) ? r*25 : 100 + (r-4)*24;
  int eCnt  = (r < 4) ? 25 : 24;

  for (int t = 0; t < 64; ++t) {
    // ---------------- P1 ----------------
    for (int i = tid; i < 512; i += 256)
      hl[i] = (_Float16)AT_LD(hpubf + b*512 + i);
    __syncthreads();
    // gate partial: Xg + Whh[grow].h  (kept in register across barriers)
    float gacc = Xg[((size_t)t*32 + b)*2048 + grow];
    {
      const half8_t* wr = (const half8_t*)(Whh_h + (size_t)grow*512);
      const half8_t* hh = (const half8_t*)hl;
      for (int k8 = 0; k8 < 64; k8++) {
        half8_t w8 = wr[k8]; half8_t h8 = hh[k8];
        const half2_t* wp = (const half2_t*)&w8;
        const half2_t* hp = (const half2_t*)&h8;
        gacc = fdot2f(wp[0], hp[0], gacc);
        gacc = fdot2f(wp[1], hp[1], gacc);
        gacc = fdot2f(wp[2], hp[2], gacc);
        gacc = fdot2f(wp[3], hp[3], gacc);
      }
    }
    // hW slice: dims [r*64, r*64+64), 4 threads per dim
    {
      int dloc = tid >> 2, s = tid & 3;
      const half8_t* wr = (const half8_t*)(Wdec_h + (size_t)(r*64 + dloc)*512 + s*128);
      const half8_t* hh = (const half8_t*)(hl + s*128);
      float a = 0.f;
      for (int k8 = 0; k8 < 16; k8++) {
        half8_t w8 = wr[k8]; half8_t h8 = hh[k8];
        const half2_t* wp = (const half2_t*)&w8;
        const half2_t* hp = (const half2_t*)&h8;
        a = fdot2f(wp[0], hp[0], a);
        a = fdot2f(wp[1], hp[1], a);
        a = fdot2f(wp[2], hp[2], a);
        a = fdot2f(wp[3], hp[3], a);
      }
      redA[tid] = a;
    }
    __syncthreads();
    if (tid < 64)
      AT_ST(hw_g + b*512 + r*64 + tid,
            redA[tid*4] + redA[tid*4+1] + redA[tid*4+2] + redA[tid*4+3]);
    group_barrier(gbar);   // bar1: hw_g ready

    // ---------------- P2: e rows [eBase, eBase+eCnt) ----------------
    for (int i = tid; i < 512; i += 256) hwl[i] = AT_LD(hw_g + b*512 + i);
    __syncthreads();
    {
      int s = tid >> 5, nloc = tid & 31;       // lanes share s -> LDS broadcast reads
      if (nloc < eCnt) {
        int n = eBase + nloc;
        const half8_t* fp8 = (const half8_t*)(fproj_h + ((size_t)b*196 + n)*512 + s*64);
        float a = 0.f;
        for (int k8 = 0; k8 < 8; k8++) {
          half8_t f = fp8[k8];
          #pragma unroll
          for (int j = 0; j < 8; j++) {
            int k = s*64 + k8*8 + j;
            a += vl[k] * fast_tanh((float)f[j] + hwl[k]);
          }
        }
        ep[nloc][s] = a;
      }
    }
    __syncthreads();
    if (tid < eCnt) {
      float e = 0.f;
      #pragma unroll
      for (int s = 0; s < 8; s++) e += ep[tid][s];
      AT_ST(e_g + b*256 + eBase + tid, e);
    }
    group_barrier(gbar);   // bar2: e ready

    // ---------------- P3: softmax (replicated) + gates + pointwise ----------------
    float ee = (tid < 196) ? AT_LD(e_g + b*256 + tid) : -1e30f;
    redA[tid] = ee;
    __syncthreads();
    for (int s = 128; s > 0; s >>= 1) {
      if (tid < s) redA[tid] = fmaxf(redA[tid], redA[tid+s]);
      __syncthreads();
    }
    float mx = redA[0];
    __syncthreads();
    float ex = (tid < 196) ? __expf(ee - mx) : 0.f;
    redA[tid] = ex;
    __syncthreads();
    for (int s = 128; s > 0; s >>= 1) {
      if (tid < s) redA[tid] += redA[tid+s];
      __syncthreads();
    }
    float al = ex * (1.f / redA[0]);
    sa[tid] = al;
    if (tid >= eBase && tid < eBase + eCnt)    // distributed alpha write
      out_alpha[((size_t)b*64 + t)*196 + tid] = al;
    __syncthreads();
    // gates: gacc + sum_n alpha[n] * P[b][n][grow]; P fully LDS-pinned
    {
      const half2_t* P2 = (const half2_t*)P_lds;
      const float2*  sap = (const float2*)sa;
      #pragma unroll 7
      for (int n2 = 0; n2 < 98; n2++) {
        half2_t p = P2[n2*256 + tid];
        float2 s2 = sap[n2];
        gacc += s2.x*(float)p[0] + s2.y*(float)p[1];
      }
    }
    sm_g[tid] = gacc;
    __syncthreads();
    if (tid < 64) {
      float ig = sm_g[tid], fg = sm_g[64+tid], gg = sm_g[128+tid], og = sm_g[192+tid];
      float cn = fast_sig(fg)*c_reg + fast_sig(ig)*fast_tanh(gg);
      float hn = fast_sig(og)*fast_tanh(cn);
      c_reg = cn;
      AT_ST(hpubf + b*512 + r*64 + tid, hn);
      H_h[((size_t)t*32 + b)*512 + r*64 + tid] = (_Float16)hn;
    }
    group_barrier(gbar);   // bar3: h ready for next step
  }
}

// ---- logits: out[b][t][:] = H[t*32+b] @ Wfc^T + bfc ----
// Persistent-N: each block owns a 128-col stripe of Wfc, loops over its m-tiles.
// grid (250, 2): y splits the 32 m-tiles 2-way.
__global__ void __launch_bounds__(512) logits_k(const _Float16* __restrict__ A,
    const _Float16* __restrict__ Bw, float* __restrict__ C,
    const float* __restrict__ bias) {
  int wave = threadIdx.x >> 6, lane = threadIdx.x & 63;
  int lr = lane & 15, quad = lane >> 4;
  int waveM = wave >> 1, waveN = wave & 1;
  int n0 = blockIdx.x*128 + waveN*64;
  const _Float16* Bp = Bw + (size_t)(n0 + lr)*512 + quad*8;
  float bv[4];
  #pragma unroll
  for (int ni = 0; ni < 4; ni++) bv[ni] = bias[n0 + ni*16 + lr];
  for (int it = 0; it < 4; ++it) {
    int m0 = (blockIdx.y*16 + it*4 + waveM)*64;
    const _Float16* Ap = A + (size_t)(m0 + lr)*512 + quad*8;
    float4_t acc[4][4];
    #pragma unroll
    for (int i = 0; i < 4; i++)
      #pragma unroll
      for (int j = 0; j < 4; j++)
        acc[i][j] = (float4_t){0.f, 0.f, 0.f, 0.f};
    for (int k0 = 0; k0 < 512; k0 += 32) {
      half8_t af[4], bf[4];
      #pragma unroll
      for (int i = 0; i < 4; i++) af[i] = *(const half8_t*)(Ap + (size_t)i*16*512 + k0);
      #pragma unroll
      for (int i = 0; i < 4; i++) bf[i] = *(const half8_t*)(Bp + (size_t)i*16*512 + k0);
      #pragma unroll
      for (int mi = 0; mi < 4; mi++)
        #pragma unroll
        for (int ni = 0; ni < 4; ni++)
          acc[mi][ni] = __builtin_amdgcn_mfma_f32_16x16x32_f16(af[mi], bf[ni], acc[mi][ni], 0, 0, 0);
    }
    #pragma unroll
    for (int mi = 0; mi < 4; mi++) {
      #pragma unroll
      for (int ni = 0; ni < 4; ni++) {
        int col = n0 + ni*16 + lr;
        #pragma unroll
        for (int r = 0; r < 4; r++) {
          int row = m0 + mi*16 + quad*4 + r;
          size_t orow = (size_t)((row & 31)*64 + (row >> 5));
          __builtin_nontemporal_store(acc[mi][ni][r] + bv[ni], C + orow*32000 + col);
        }
      }
    }
  }
}

extern "C" void kernel_launch(void* const* d_in, const int* in_sizes, int n_in,
                              void* d_out, int out_size, void* d_ws, size_t ws_size,
                              hipStream_t stream) {
  const float* imgf  = (const float*)d_in[0];
  const int*   cap   = (const int*)d_in[1];
  const float* emb   = (const float*)d_in[2];
  const float* Wh0   = (const float*)d_in[3];
  const float* bh0   = (const float*)d_in[4];
  const float* Wc0   = (const float*)d_in[5];
  const float* bc0   = (const float*)d_in[6];
  const float* Wenc  = (const float*)d_in[7];
  const float* Wdec  = (const float*)d_in[8];
  const float* v_att = (const float*)d_in[9];
  const float* W_ih  = (const float*)d_in[10];
  const float* b_ih  = (const float*)d_in[11];
  const float* W_hh  = (const float*)d_in[12];
  const float* b_hh  = (const float*)d_in[13];
  const float* Wfc   = (const float*)d_in[14];
  const float* bfc   = (const float*)d_in[15];
  float* out = (float*)d_out;
  (void)in_sizes; (void)n_in; (void)out_size; (void)ws_size;

  char* ws = (char*)d_ws;
  size_t off = 0;
  auto alloc = [&](size_t bytes) -> void* {
    void* p = ws + off;
    off += (bytes + 255) & ~(size_t)255;
    return p;
  };
  _Float16* Wenc_h  = (_Float16*)alloc((size_t)512*512*2);
  _Float16* Wdec_h  = (_Float16*)alloc((size_t)512*512*2);
  _Float16* Wih_h   = (_Float16*)alloc((size_t)2048*1024*2);
  _Float16* Whh_h   = (_Float16*)alloc((size_t)2048*512*2);
  _Float16* Wfc_h   = (_Float16*)alloc((size_t)32000*512*2);
  _Float16* imgf_h  = (_Float16*)alloc((size_t)32*196*512*2);
  _Float16* fproj_h = (_Float16*)alloc((size_t)32*196*512*2);
  _Float16* P_T     = (_Float16*)alloc((size_t)32*2048*PTLD*2);
  _Float16* X_h     = (_Float16*)alloc((size_t)64*32*512*2);
  float*    Xg      = (float*)alloc((size_t)64*32*2048*4);
  float*    bsum    = (float*)alloc((size_t)2048*4);
  float*    c_state = (float*)alloc((size_t)32*512*4);
  float*    hpubf   = (float*)alloc((size_t)32*512*4);
  float*    hw_g    = (float*)alloc((size_t)32*512*4);
  float*    e_g     = (float*)alloc((size_t)32*256*4);
  _Float16* H_h     = (_Float16*)alloc((size_t)2048*512*2);
  unsigned* bar     = (unsigned*)alloc((size_t)4096);

  auto cvt = [&](const float* s, _Float16* d, int n) {
    cvt_k<<<dim3((n/4 + 255)/256), dim3(256), 0, stream>>>(s, d, n);
  };
  cvt(Wenc, Wenc_h, 512*512);
  cvt(Wdec, Wdec_h, 512*512);
  cvt(W_ih, Wih_h, 2048*1024);
  cvt(W_hh, Whh_h, 2048*512);
  cvt(Wfc,  Wfc_h, 32000*512);
  cvt(imgf, imgf_h, 32*196*512);
  bias_sum_k<<<dim3(8), dim3(256), 0, stream>>>(b_ih, b_hh, bsum, bar);
  gather_emb_k<<<dim3(2048), dim3(256), 0, stream>>>(emb, cap, X_h);
  init_state_k<<<dim3(32), dim3(256), 0, stream>>>(imgf, Wh0, bh0, Wc0, bc0, c_state, hpubf);
  // feat_proj = image_features @ Wenc^T  -> fp16 [32*196, 512]
  gemm_abt_k<1><<<dim3(4, 49), dim3(256), 0, stream>>>(imgf_h, 512, Wenc_h, 512, fproj_h, 512, nullptr, 512);
  // P_T[b] = W_ih[:,512:] @ imgf[b]^T  -> fp16 [32][2048][PTLD]
  gemm_pt_k<<<dim3(2, 16, 32), dim3(256), 0, stream>>>(Wih_h + 512, imgf_h, P_T);
  // Xg = emb_x @ W_ih[:, :512]^T + (b_ih + b_hh)  -> fp32 [2048, 2048]
  gemm_abt_k<0><<<dim3(16, 16), dim3(256), 0, stream>>>(X_h, 512, Wih_h, 1024, Xg, 2048, bsum, 512);

  float* out_alpha = out + (size_t)32*64*32000;
  // all 64 recurrence steps in one persistent launch (32 groups x 8 blocks)
  loop_k<<<dim3(256), dim3(256), 0, stream>>>(Wdec_h, Whh_h, fproj_h, P_T, Xg,
      v_att, c_state, hpubf, hw_g, e_g, H_h, out_alpha, bar);
  // outputs = H @ Wfc^T + bfc (remapped rows)
  logits_k<<<dim3(250, 2), dim3(512), 0, stream>>>(H_h, Wfc_h, out, bfc);
}

// Round 5
// 2092.658 us; speedup vs baseline: 6.2007x; 1.3860x over previous
//
#include <hip/hip_runtime.h>
#include <cstdint>
#include <cstddef>

typedef _Float16 half2_t __attribute__((ext_vector_type(2)));
typedef _Float16 half4_t __attribute__((ext_vector_type(4)));
typedef _Float16 half8_t __attribute__((ext_vector_type(8)));
typedef float    float4_t __attribute__((ext_vector_type(4)));

#define CAPLEN 65
#define PTLD 200       // P_T / fproj_T row stride in halfs (196 used)

#define AT_LD(p)     __hip_atomic_load((p), __ATOMIC_RELAXED, __HIP_MEMORY_SCOPE_AGENT)
#define AT_ST(p, v)  __hip_atomic_store((p), (v), __ATOMIC_RELAXED, __HIP_MEMORY_SCOPE_AGENT)

#if defined(__has_builtin)
#if __has_builtin(__builtin_amdgcn_fdot2)
#define HAS_FDOT2 1
#endif
#endif

__device__ __forceinline__ float fdot2f(half2_t a, half2_t b, float c) {
#ifdef HAS_FDOT2
  return __builtin_amdgcn_fdot2(a, b, c, false);
#else
  return c + (float)a[0]*(float)b[0] + (float)a[1]*(float)b[1];
#endif
}

__device__ __forceinline__ float fast_tanh(float x) {
  float e = __expf(2.f*x);
  return 1.f - 2.f/(e + 1.f);
}
__device__ __forceinline__ float fast_sig(float x) {
  return 1.f/(1.f + __expf(-x));
}

// ---------- fp32 -> fp16 convert (n % 4 == 0) ----------
__global__ void cvt_k(const float* __restrict__ s, _Float16* __restrict__ d, int n) {
  int i = (blockIdx.x*blockDim.x + threadIdx.x)*4;
  if (i < n) {
    float4 v = *(const float4*)(s + i);
    half4_t h;
    h[0] = (_Float16)v.x; h[1] = (_Float16)v.y; h[2] = (_Float16)v.z; h[3] = (_Float16)v.w;
    *(half4_t*)(d + i) = h;
  }
}

// bias sum + zero the barrier slots
__global__ void bias_sum_k(const float* __restrict__ a, const float* __restrict__ b,
                           float* __restrict__ o, unsigned* __restrict__ bar) {
  int i = blockIdx.x*blockDim.x + threadIdx.x;
  if (i < 2048) o[i] = a[i] + b[i];
  if (i < 1024) bar[i] = 0u;
}

// gather embeddings for all (t,b): row r = t*32 + b, token = captions[b][t]
__global__ void gather_emb_k(const float* __restrict__ emb, const int* __restrict__ cap,
                             _Float16* __restrict__ X) {
  int r = blockIdx.x;
  int t = r >> 5, b = r & 31;
  int tok = cap[b*CAPLEN + t];
  const float* s = emb + (size_t)tok*512;
  _Float16* d = X + (size_t)r*512;
  for (int k = threadIdx.x; k < 512; k += blockDim.x) d[k] = (_Float16)s[k];
}

// feat_mean -> h0 (packed half2, published), c0 (fp32); one wg (256 thr) per b
__global__ void init_state_k(const float* __restrict__ imgf,
                             const float* __restrict__ Wh0, const float* __restrict__ bh0,
                             const float* __restrict__ Wc0, const float* __restrict__ bc0,
                             float* __restrict__ c_state, unsigned* __restrict__ hpub2) {
  __shared__ float fm[512];
  __shared__ float hsh[512];
  int b = blockIdx.x, tid = threadIdx.x;
  for (int dI = tid; dI < 512; dI += 256) {
    float s = 0.f;
    const float* p = imgf + ((size_t)b*196)*512 + dI;
    for (int n = 0; n < 196; n++) s += p[(size_t)n*512];
    fm[dI] = s * (1.f/196.f);
  }
  __syncthreads();
  for (int dI = tid; dI < 512; dI += 256) {
    const float* wh = Wh0 + (size_t)dI*512;
    const float* wc = Wc0 + (size_t)dI*512;
    float h = bh0[dI], c = bc0[dI];
    for (int k = 0; k < 512; k++) { h += fm[k]*wh[k]; c += fm[k]*wc[k]; }
    hsh[dI] = h;
    c_state[b*512 + dI] = c;
  }
  __syncthreads();
  {
    half2_t h2; h2[0] = (_Float16)hsh[2*tid]; h2[1] = (_Float16)hsh[2*tid+1];
    union { half2_t h; unsigned u; } cv; cv.h = h2;
    hpub2[b*256 + tid] = cv.u;
  }
}

// Generic C = A * B^T (+bias), fp16 in, fp32 acc, MFMA 16x16x32.
// MODE 0: fp32 C (+bias). MODE 1: fp16 C.
template<int MODE>
__global__ void __launch_bounds__(256) gemm_abt_k(const _Float16* __restrict__ A, int lda,
    const _Float16* __restrict__ B, int ldb, void* __restrict__ Cp, int ldc,
    const float* __restrict__ bias, int K) {
  int wave = threadIdx.x >> 6, lane = threadIdx.x & 63;
  int m0 = blockIdx.y*128 + (wave >> 1)*64;
  int n0 = blockIdx.x*128 + (wave & 1)*64;
  int lr = lane & 15, quad = lane >> 4;
  float4_t acc[4][4];
  #pragma unroll
  for (int i = 0; i < 4; i++)
    #pragma unroll
    for (int j = 0; j < 4; j++)
      acc[i][j] = (float4_t){0.f, 0.f, 0.f, 0.f};
  const _Float16* Ap = A + (size_t)(m0 + lr)*lda + quad*8;
  const _Float16* Bp = B + (size_t)(n0 + lr)*ldb + quad*8;
  for (int k0 = 0; k0 < K; k0 += 32) {
    half8_t af[4], bf[4];
    #pragma unroll
    for (int i = 0; i < 4; i++) af[i] = *(const half8_t*)(Ap + (size_t)i*16*lda + k0);
    #pragma unroll
    for (int i = 0; i < 4; i++) bf[i] = *(const half8_t*)(Bp + (size_t)i*16*ldb + k0);
    #pragma unroll
    for (int mi = 0; mi < 4; mi++)
      #pragma unroll
      for (int ni = 0; ni < 4; ni++)
        acc[mi][ni] = __builtin_amdgcn_mfma_f32_16x16x32_f16(af[mi], bf[ni], acc[mi][ni], 0, 0, 0);
  }
  #pragma unroll
  for (int mi = 0; mi < 4; mi++) {
    #pragma unroll
    for (int ni = 0; ni < 4; ni++) {
      int col = n0 + ni*16 + lr;
      float bv = (MODE == 1) ? 0.f : bias[col];
      #pragma unroll
      for (int r = 0; r < 4; r++) {
        int row = m0 + mi*16 + quad*4 + r;
        if (MODE == 1) {
          ((_Float16*)Cp)[(size_t)row*ldc + col] = (_Float16)acc[mi][ni][r];
        } else {
          ((float*)Cp)[(size_t)row*ldc + col] = acc[mi][ni][r] + bv;
        }
      }
    }
  }
}

// C[b][row][n] = sum_k A[row][k] * imgf[b][n][k]   (fp16 out, ldc=PTLD)
// grid (nx, my, 32): x = n-tile(128), y = m-tile(128), z = b
__global__ void __launch_bounds__(256) gemm_pt_k(const _Float16* __restrict__ A, int lda,
    const _Float16* __restrict__ Bimg, _Float16* __restrict__ Cpt, int mrows) {
  int z = blockIdx.z;
  const _Float16* B = Bimg + (size_t)z*196*512;   // rows >=196 read OOB garbage; masked downstream
  _Float16* C = Cpt + (size_t)z*mrows*PTLD;
  int wave = threadIdx.x >> 6, lane = threadIdx.x & 63;
  int m0 = blockIdx.y*128 + (wave >> 1)*64;
  int n0 = blockIdx.x*128 + (wave & 1)*64;
  int lr = lane & 15, quad = lane >> 4;
  float4_t acc[4][4];
  #pragma unroll
  for (int i = 0; i < 4; i++)
    #pragma unroll
    for (int j = 0; j < 4; j++)
      acc[i][j] = (float4_t){0.f, 0.f, 0.f, 0.f};
  const _Float16* Ap = A + (size_t)(m0 + lr)*lda + quad*8;
  const _Float16* Bp = B + (size_t)(n0 + lr)*512 + quad*8;
  for (int k0 = 0; k0 < 512; k0 += 32) {
    half8_t af[4], bf[4];
    #pragma unroll
    for (int i = 0; i < 4; i++) af[i] = *(const half8_t*)(Ap + (size_t)i*16*lda + k0);
    #pragma unroll
    for (int i = 0; i < 4; i++) bf[i] = *(const half8_t*)(Bp + (size_t)i*16*512 + k0);
    #pragma unroll
    for (int mi = 0; mi < 4; mi++)
      #pragma unroll
      for (int ni = 0; ni < 4; ni++)
        acc[mi][ni] = __builtin_amdgcn_mfma_f32_16x16x32_f16(af[mi], bf[ni], acc[mi][ni], 0, 0, 0);
  }
  #pragma unroll
  for (int mi = 0; mi < 4; mi++) {
    #pragma unroll
    for (int ni = 0; ni < 4; ni++) {
      int col = n0 + ni*16 + lr;
      if (col < PTLD) {
        #pragma unroll
        for (int r = 0; r < 4; r++) {
          int row = m0 + mi*16 + quad*4 + r;
          C[(size_t)row*PTLD + col] = (_Float16)acc[mi][ni][r];
        }
      }
    }
  }
}

// ---- store/poll group barrier: no RMW, no acquire, no wbl2 ----
// Preceding __syncthreads drains EVERY wave's vmcnt (payload stores at L3),
// then one relaxed store publishes the epoch; 8 threads poll the 8 slots.
__device__ __forceinline__ void sbar(unsigned* __restrict__ slots, int r,
                                     unsigned target, int tid) {
  __syncthreads();
  if (tid == 0) AT_ST(slots + r, target);
  if (tid < 8) {
    while (AT_LD(slots + tid) < target) __builtin_amdgcn_s_sleep(1);
  }
  __syncthreads();
}

// ---- persistent recurrence: 32 groups (one per b) of 8 blocks (one per r-slice) ----
// r = bid & 7 -> same-r blocks share an XCD (Whh/Wdec slices L2-resident).
// 512 threads (2 waves/SIMD). Per step, 2 cross-block barriers:
//   hl pull -> hW slice (shfl-reduced) -> e-partials over OWN dims -> publish e
//   -> gacc = Xg + Whh.h (big L2 read; hides barrier skew) -> BAR_E
//   -> softmax (replicated, from summed partials) -> gates (P in LDS) -> pointwise
//   -> publish packed h -> BAR_H
__global__ void __launch_bounds__(512) loop_k(
    const _Float16* __restrict__ Wdec_h,   // [512][512]
    const _Float16* __restrict__ Whh_h,    // [2048][512]
    const _Float16* __restrict__ fproj_T,  // [32][512][PTLD]
    const _Float16* __restrict__ P_T,      // [32][2048][PTLD]
    const float*    __restrict__ Xg,       // [64*32][2048]
    const float*    __restrict__ v_att,    // [512]
    const float*    __restrict__ c_init,   // [32][512]
    unsigned*       __restrict__ hpub2,    // [32][256] packed half2 (atomic)
    float*          __restrict__ epub,     // [32][8][256] fp32 partial e (atomic)
    _Float16*       __restrict__ H_h,      // [64*32][512]
    float*          __restrict__ out_alpha,// [32][64][196]
    unsigned*       __restrict__ bar) {
  __shared__ _Float16 P_lds[98*256*2];     // [n2][row][2] half2-interleaved, 100352B
  __shared__ _Float16 fp_lds[64*PTLD];     // fproj_T slice [dloc][n], 25600B
  __shared__ __align__(16) unsigned hl_u[256]; // h as packed half2
  __shared__ float vlf[64];
  __shared__ float hwf[64];
  __shared__ float ep[2][256];
  __shared__ float redA[8];
  __shared__ float redB[8];
  __shared__ float sa[256];
  __shared__ float sm2[512];
  __shared__ float hnl[64];
  int bid = blockIdx.x, tid = threadIdx.x;
  int r = bid & 7, b = bid >> 3;
  unsigned* slots = bar + b*32;
  int row = tid & 255, half = tid >> 8;
  int typ = row >> 6, dl = row & 63;
  int grow = typ*512 + r*64 + dl;          // gate row owned by (thread row)
  int lane = tid & 63;

  if (tid < 64) vlf[tid] = v_att[r*64 + tid];
  float c_reg = (tid < 64) ? c_init[b*512 + r*64 + tid] : 0.f;

  // one-time staging: P rows (tid<256) and fproj_T slice (tid>=256)
  if (tid < 256) {
    const _Float16* pp = P_T + ((size_t)b*2048 + grow)*PTLD;
    half2_t* P2 = (half2_t*)P_lds;
    for (int k8 = 0; k8 < 24; k8++) {
      half8_t v8 = *(const half8_t*)(pp + k8*8);
      #pragma unroll
      for (int j2 = 0; j2 < 4; j2++) {
        half2_t h2; h2[0] = v8[2*j2]; h2[1] = v8[2*j2+1];
        P2[(k8*4 + j2)*256 + row] = h2;
      }
    }
    half4_t v4 = *(const half4_t*)(pp + 192);
    half2_t a2; a2[0] = v4[0]; a2[1] = v4[1];
    half2_t b2; b2[0] = v4[2]; b2[1] = v4[3];
    P2[96*256 + row] = a2;
    P2[97*256 + row] = b2;
  } else {
    for (int i = tid - 256; i < 64*25; i += 256) {
      int d = i/25, c = i - d*25;
      *(half8_t*)(fp_lds + d*PTLD + c*8) =
        *(const half8_t*)(fproj_T + ((size_t)(b*512 + r*64 + d))*PTLD + c*8);
    }
  }
  int eBase = (r < 4) ? r*25 : 100 + (r-4)*24;
  int eCnt  = (r < 4) ? 25 : 24;

  for (int t = 0; t < 64; ++t) {
    // 1. pull published h (packed half2 via L3)
    if (tid < 256) hl_u[tid] = AT_LD(hpub2 + b*256 + tid);
    float xg = (half == 0) ? Xg[((size_t)t*32 + b)*2048 + grow] : 0.f;
    __syncthreads();
    // 2. hW own slice: thread = dim*8 + s, shfl-reduce over s
    {
      int dim = tid >> 3, s = tid & 7;
      const half8_t* wr = (const half8_t*)(Wdec_h + (size_t)(r*64 + dim)*512 + s*64);
      const half8_t* hh = ((const half8_t*)(const _Float16*)hl_u) + s*8;
      float a = 0.f;
      #pragma unroll
      for (int k8 = 0; k8 < 8; k8++) {
        half8_t w8 = wr[k8]; half8_t h8 = hh[k8];
        const half2_t* wp = (const half2_t*)&w8;
        const half2_t* hp = (const half2_t*)&h8;
        a = fdot2f(wp[0], hp[0], a);
        a = fdot2f(wp[1], hp[1], a);
        a = fdot2f(wp[2], hp[2], a);
        a = fdot2f(wp[3], hp[3], a);
      }
      a += __shfl_xor(a, 1);
      a += __shfl_xor(a, 2);
      a += __shfl_xor(a, 4);
      if (s == 0) hwf[dim] = a;
    }
    __syncthreads();
    // 3. e-partials over own 64 dims: thread = (n=row, dgroup=half)
    {
      float a = 0.f;
      if (row < 196) {
        #pragma unroll 8
        for (int j = 0; j < 32; j++) {
          int dd = half*32 + j;
          a += vlf[dd] * fast_tanh((float)fp_lds[dd*PTLD + row] + hwf[dd]);
        }
      }
      ep[half][row] = a;
    }
    __syncthreads();
    // 4. publish e partial
    if (tid < 196) AT_ST(epub + ((size_t)b*8 + r)*256 + tid, ep[0][tid] + ep[1][tid]);
    // 5. gacc = Xg + Whh[grow].h (split-K); big L2 read overlaps barrier skew
    float gacc = xg;
    {
      const half8_t* wr = (const half8_t*)(Whh_h + (size_t)grow*512 + half*256);
      const half8_t* hh = ((const half8_t*)(const _Float16*)hl_u) + half*32;
      for (int k8 = 0; k8 < 32; k8++) {
        half8_t w8 = wr[k8]; half8_t h8 = hh[k8];
        const half2_t* wp = (const half2_t*)&w8;
        const half2_t* hp = (const half2_t*)&h8;
        gacc = fdot2f(wp[0], hp[0], gacc);
        gacc = fdot2f(wp[1], hp[1], gacc);
        gacc = fdot2f(wp[2], hp[2], gacc);
        gacc = fdot2f(wp[3], hp[3], gacc);
      }
    }
    sbar(slots, r, 2*(unsigned)t + 1, tid);   // BAR_E

    // 6. softmax (replicated): sum the 8 dim-partials, wave-reduce max/sum
    float ee = -1e30f;
    if (tid < 196) {
      float s0 = 0.f;
      #pragma unroll
      for (int rr = 0; rr < 8; rr++)
        s0 += AT_LD(epub + ((size_t)b*8 + rr)*256 + tid);
      ee = s0;
    }
    {
      float m = ee;
      #pragma unroll
      for (int off = 32; off > 0; off >>= 1) m = fmaxf(m, __shfl_xor(m, off));
      if (lane == 0) redA[tid >> 6] = m;
    }
    __syncthreads();
    float mx = redA[0];
    #pragma unroll
    for (int i = 1; i < 8; i++) mx = fmaxf(mx, redA[i]);
    float ex = (tid < 196) ? __expf(ee - mx) : 0.f;
    {
      float s = ex;
      #pragma unroll
      for (int off = 32; off > 0; off >>= 1) s += __shfl_xor(s, off);
      if (lane == 0) redB[tid >> 6] = s;
    }
    __syncthreads();
    float tot = redB[0];
    #pragma unroll
    for (int i = 1; i < 8; i++) tot += redB[i];
    float al = ex * (1.f/tot);
    if (tid < 256) sa[tid] = al;
    if (tid >= eBase && tid < eBase + eCnt)
      out_alpha[((size_t)b*64 + t)*196 + tid] = al;
    __syncthreads();
    // 7. gates: gacc += alpha . P (split-n over halves; P fully LDS-pinned)
    {
      const half2_t* P2 = (const half2_t*)P_lds;
      const float2*  sap = (const float2*)sa;
      int n2b = half*49;
      #pragma unroll 7
      for (int n2 = n2b; n2 < n2b + 49; n2++) {
        half2_t p = P2[n2*256 + row];
        float2 s2 = sap[n2];
        gacc += s2.x*(float)p[0] + s2.y*(float)p[1];
      }
      sm2[tid] = gacc;
    }
    __syncthreads();
    // 8. pointwise LSTM (c in registers)
    if (tid < 64) {
      float ig = sm2[tid]       + sm2[tid + 256];
      float fg = sm2[64 + tid]  + sm2[tid + 320];
      float gg = sm2[128 + tid] + sm2[tid + 384];
      float og = sm2[192 + tid] + sm2[tid + 448];
      float cn = fast_sig(fg)*c_reg + fast_sig(ig)*fast_tanh(gg);
      float hn = fast_sig(og)*fast_tanh(cn);
      c_reg = cn;
      hnl[tid] = hn;
      H_h[((size_t)t*32 + b)*512 + r*64 + tid] = (_Float16)hn;
    }
    __syncthreads();
    // 9. publish packed h slice
    if (tid < 32) {
      half2_t h2; h2[0] = (_Float16)hnl[2*tid]; h2[1] = (_Float16)hnl[2*tid+1];
      union { half2_t h; unsigned u; } cv; cv.h = h2;
      AT_ST(hpub2 + b*256 + r*32 + tid, cv.u);
    }
    sbar(slots, r, 2*(unsigned)t + 2, tid);   // BAR_H
  }
}

// ---- logits: out[b][t][:] = H[t*32+b] @ Wfc^T + bfc ----
__global__ void __launch_bounds__(512) logits_k(const _Float16* __restrict__ A,
    const _Float16* __restrict__ Bw, float* __restrict__ C,
    const float* __restrict__ bias) {
  int wave = threadIdx.x >> 6, lane = threadIdx.x & 63;
  int lr = lane & 15, quad = lane >> 4;
  int waveM = wave >> 1, waveN = wave & 1;
  int n0 = blockIdx.x*128 + waveN*64;
  const _Float16* Bp = Bw + (size_t)(n0 + lr)*512 + quad*8;
  float bv[4];
  #pragma unroll
  for (int ni = 0; ni < 4; ni++) bv[ni] = bias[n0 + ni*16 + lr];
  for (int it = 0; it < 4; ++it) {
    int m0 = (blockIdx.y*16 + it*4 + waveM)*64;
    const _Float16* Ap = A + (size_t)(m0 + lr)*512 + quad*8;
    float4_t acc[4][4];
    #pragma unroll
    for (int i = 0; i < 4; i++)
      #pragma unroll
      for (int j = 0; j < 4; j++)
        acc[i][j] = (float4_t){0.f, 0.f, 0.f, 0.f};
    for (int k0 = 0; k0 < 512; k0 += 32) {
      half8_t af[4], bf[4];
      #pragma unroll
      for (int i = 0; i < 4; i++) af[i] = *(const half8_t*)(Ap + (size_t)i*16*512 + k0);
      #pragma unroll
      for (int i = 0; i < 4; i++) bf[i] = *(const half8_t*)(Bp + (size_t)i*16*512 + k0);
      #pragma unroll
      for (int mi = 0; mi < 4; mi++)
        #pragma unroll
        for (int ni = 0; ni < 4; ni++)
          acc[mi][ni] = __builtin_amdgcn_mfma_f32_16x16x32_f16(af[mi], bf[ni], acc[mi][ni], 0, 0, 0);
    }
    #pragma unroll
    for (int mi = 0; mi < 4; mi++) {
      #pragma unroll
      for (int ni = 0; ni < 4; ni++) {
        int col = n0 + ni*16 + lr;
        #pragma unroll
        for (int r = 0; r < 4; r++) {
          int row = m0 + mi*16 + quad*4 + r;
          size_t orow = (size_t)((row & 31)*64 + (row >> 5));
          __builtin_nontemporal_store(acc[mi][ni][r] + bv[ni], C + orow*32000 + col);
        }
      }
    }
  }
}

extern "C" void kernel_launch(void* const* d_in, const int* in_sizes, int n_in,
                              void* d_out, int out_size, void* d_ws, size_t ws_size,
                              hipStream_t stream) {
  const float* imgf  = (const float*)d_in[0];
  const int*   cap   = (const int*)d_in[1];
  const float* emb   = (const float*)d_in[2];
  const float* Wh0   = (const float*)d_in[3];
  const float* bh0   = (const float*)d_in[4];
  const float* Wc0   = (const float*)d_in[5];
  const float* bc0   = (const float*)d_in[6];
  const float* Wenc  = (const float*)d_in[7];
  const float* Wdec  = (const float*)d_in[8];
  const float* v_att = (const float*)d_in[9];
  const float* W_ih  = (const float*)d_in[10];
  const float* b_ih  = (const float*)d_in[11];
  const float* W_hh  = (const float*)d_in[12];
  const float* b_hh  = (const float*)d_in[13];
  const float* Wfc   = (const float*)d_in[14];
  const float* bfc   = (const float*)d_in[15];
  float* out = (float*)d_out;
  (void)in_sizes; (void)n_in; (void)out_size; (void)ws_size;

  char* ws = (char*)d_ws;
  size_t off = 0;
  auto alloc = [&](size_t bytes) -> void* {
    void* p = ws + off;
    off += (bytes + 255) & ~(size_t)255;
    return p;
  };
  _Float16* Wenc_h  = (_Float16*)alloc((size_t)512*512*2);
  _Float16* Wdec_h  = (_Float16*)alloc((size_t)512*512*2);
  _Float16* Wih_h   = (_Float16*)alloc((size_t)2048*1024*2);
  _Float16* Whh_h   = (_Float16*)alloc((size_t)2048*512*2);
  _Float16* Wfc_h   = (_Float16*)alloc((size_t)32000*512*2);
  _Float16* imgf_h  = (_Float16*)alloc((size_t)32*196*512*2);
  _Float16* fproj_T = (_Float16*)alloc((size_t)32*512*PTLD*2);
  _Float16* P_T     = (_Float16*)alloc((size_t)32*2048*PTLD*2);
  _Float16* X_h     = (_Float16*)alloc((size_t)64*32*512*2);
  float*    Xg      = (float*)alloc((size_t)64*32*2048*4);
  float*    bsum    = (float*)alloc((size_t)2048*4);
  float*    c_state = (float*)alloc((size_t)32*512*4);
  unsigned* hpub2   = (unsigned*)alloc((size_t)32*256*4);
  float*    epub    = (float*)alloc((size_t)32*8*256*4);
  _Float16* H_h     = (_Float16*)alloc((size_t)2048*512*2);
  unsigned* bar     = (unsigned*)alloc((size_t)4096);

  auto cvt = [&](const float* s, _Float16* d, int n) {
    cvt_k<<<dim3((n/4 + 255)/256), dim3(256), 0, stream>>>(s, d, n);
  };
  cvt(Wenc, Wenc_h, 512*512);
  cvt(Wdec, Wdec_h, 512*512);
  cvt(W_ih, Wih_h, 2048*1024);
  cvt(W_hh, Whh_h, 2048*512);
  cvt(Wfc,  Wfc_h, 32000*512);
  cvt(imgf, imgf_h, 32*196*512);
  bias_sum_k<<<dim3(8), dim3(256), 0, stream>>>(b_ih, b_hh, bsum, bar);
  gather_emb_k<<<dim3(2048), dim3(256), 0, stream>>>(emb, cap, X_h);
  init_state_k<<<dim3(32), dim3(256), 0, stream>>>(imgf, Wh0, bh0, Wc0, bc0, c_state, hpub2);
  // fproj_T[b] = Wenc @ imgf[b]^T -> fp16 [32][512][PTLD]
  gemm_pt_k<<<dim3(2, 4, 32), dim3(256), 0, stream>>>(Wenc_h, 512, imgf_h, fproj_T, 512);
  // P_T[b] = W_ih[:,512:] @ imgf[b]^T -> fp16 [32][2048][PTLD]
  gemm_pt_k<<<dim3(2, 16, 32), dim3(256), 0, stream>>>(Wih_h + 512, 1024, imgf_h, P_T, 2048);
  // Xg = emb_x @ W_ih[:, :512]^T + (b_ih + b_hh)  -> fp32 [2048, 2048]
  gemm_abt_k<0><<<dim3(16, 16), dim3(256), 0, stream>>>(X_h, 512, Wih_h, 1024, Xg, 2048, bsum, 512);

  float* out_alpha = out + (size_t)32*64*32000;
  // all 64 recurrence steps in one persistent launch (32 groups x 8 blocks, 512 thr)
  loop_k<<<dim3(256), dim3(512), 0, stream>>>(Wdec_h, Whh_h, fproj_T, P_T, Xg,
      v_att, c_state, hpub2, epub, H_h, out_alpha, bar);
  // outputs = H @ Wfc^T + bfc (remapped rows)
  logits_k<<<dim3(250, 2), dim3(512), 0, stream>>>(H_h, Wfc_h, out, bfc);
}

// Round 6
// 2027.140 us; speedup vs baseline: 6.4011x; 1.0323x over previous
//
#include <hip/hip_runtime.h>
#include <cstdint>
#include <cstddef>

typedef _Float16 half2_t __attribute__((ext_vector_type(2)));
typedef _Float16 half4_t __attribute__((ext_vector_type(4)));
typedef _Float16 half8_t __attribute__((ext_vector_type(8)));
typedef float    float4_t __attribute__((ext_vector_type(4)));

#define CAPLEN 65
#define PTLD 200       // P_T / fproj_T row stride in halfs (196 used)
#define BARSTRIDE 32   // uints per barrier slot (128 B line) -> no false sharing

#define AT_LD(p)     __hip_atomic_load((p), __ATOMIC_RELAXED, __HIP_MEMORY_SCOPE_AGENT)
#define AT_ST(p, v)  __hip_atomic_store((p), (v), __ATOMIC_RELAXED, __HIP_MEMORY_SCOPE_AGENT)

#if defined(__has_builtin)
#if __has_builtin(__builtin_amdgcn_fdot2)
#define HAS_FDOT2 1
#endif
#endif

__device__ __forceinline__ float fdot2f(half2_t a, half2_t b, float c) {
#ifdef HAS_FDOT2
  return __builtin_amdgcn_fdot2(a, b, c, false);
#else
  return c + (float)a[0]*(float)b[0] + (float)a[1]*(float)b[1];
#endif
}

__device__ __forceinline__ float fast_tanh(float x) {
  float e = __expf(2.f*x);
  return 1.f - 2.f/(e + 1.f);
}
__device__ __forceinline__ float fast_sig(float x) {
  return 1.f/(1.f + __expf(-x));
}

// ---------- fp32 -> fp16 convert (n % 4 == 0) ----------
__global__ void cvt_k(const float* __restrict__ s, _Float16* __restrict__ d, int n) {
  int i = (blockIdx.x*blockDim.x + threadIdx.x)*4;
  if (i < n) {
    float4 v = *(const float4*)(s + i);
    half4_t h;
    h[0] = (_Float16)v.x; h[1] = (_Float16)v.y; h[2] = (_Float16)v.z; h[3] = (_Float16)v.w;
    *(half4_t*)(d + i) = h;
  }
}

// bias sum + zero the (padded) barrier slots: 32 groups x 8 slots x 32 uints
__global__ void bias_sum_k(const float* __restrict__ a, const float* __restrict__ b,
                           float* __restrict__ o, unsigned* __restrict__ bar) {
  int i = blockIdx.x*blockDim.x + threadIdx.x;
  if (i < 2048) o[i] = a[i] + b[i];
  for (int j = i; j < 32*8*BARSTRIDE; j += 2048) bar[j] = 0u;
}

// gather embeddings for all (t,b): row r = t*32 + b, token = captions[b][t]
__global__ void gather_emb_k(const float* __restrict__ emb, const int* __restrict__ cap,
                             _Float16* __restrict__ X) {
  int r = blockIdx.x;
  int t = r >> 5, b = r & 31;
  int tok = cap[b*CAPLEN + t];
  const float* s = emb + (size_t)tok*512;
  _Float16* d = X + (size_t)r*512;
  for (int k = threadIdx.x; k < 512; k += blockDim.x) d[k] = (_Float16)s[k];
}

// feat_mean -> h0 (packed half2, published), c0 (fp32); one wg (256 thr) per b
__global__ void init_state_k(const float* __restrict__ imgf,
                             const float* __restrict__ Wh0, const float* __restrict__ bh0,
                             const float* __restrict__ Wc0, const float* __restrict__ bc0,
                             float* __restrict__ c_state, unsigned* __restrict__ hpub2) {
  __shared__ float fm[512];
  __shared__ float hsh[512];
  int b = blockIdx.x, tid = threadIdx.x;
  for (int dI = tid; dI < 512; dI += 256) {
    float s = 0.f;
    const float* p = imgf + ((size_t)b*196)*512 + dI;
    for (int n = 0; n < 196; n++) s += p[(size_t)n*512];
    fm[dI] = s * (1.f/196.f);
  }
  __syncthreads();
  for (int dI = tid; dI < 512; dI += 256) {
    const float* wh = Wh0 + (size_t)dI*512;
    const float* wc = Wc0 + (size_t)dI*512;
    float h = bh0[dI], c = bc0[dI];
    for (int k = 0; k < 512; k++) { h += fm[k]*wh[k]; c += fm[k]*wc[k]; }
    hsh[dI] = h;
    c_state[b*512 + dI] = c;
  }
  __syncthreads();
  {
    half2_t h2; h2[0] = (_Float16)hsh[2*tid]; h2[1] = (_Float16)hsh[2*tid+1];
    union { half2_t h; unsigned u; } cv; cv.h = h2;
    hpub2[b*256 + tid] = cv.u;
  }
}

// Generic C = A * B^T (+bias), fp16 in, fp32 acc, MFMA 16x16x32.
// MODE 0: fp32 C (+bias). MODE 1: fp16 C.
template<int MODE>
__global__ void __launch_bounds__(256) gemm_abt_k(const _Float16* __restrict__ A, int lda,
    const _Float16* __restrict__ B, int ldb, void* __restrict__ Cp, int ldc,
    const float* __restrict__ bias, int K) {
  int wave = threadIdx.x >> 6, lane = threadIdx.x & 63;
  int m0 = blockIdx.y*128 + (wave >> 1)*64;
  int n0 = blockIdx.x*128 + (wave & 1)*64;
  int lr = lane & 15, quad = lane >> 4;
  float4_t acc[4][4];
  #pragma unroll
  for (int i = 0; i < 4; i++)
    #pragma unroll
    for (int j = 0; j < 4; j++)
      acc[i][j] = (float4_t){0.f, 0.f, 0.f, 0.f};
  const _Float16* Ap = A + (size_t)(m0 + lr)*lda + quad*8;
  const _Float16* Bp = B + (size_t)(n0 + lr)*ldb + quad*8;
  for (int k0 = 0; k0 < K; k0 += 32) {
    half8_t af[4], bf[4];
    #pragma unroll
    for (int i = 0; i < 4; i++) af[i] = *(const half8_t*)(Ap + (size_t)i*16*lda + k0);
    #pragma unroll
    for (int i = 0; i < 4; i++) bf[i] = *(const half8_t*)(Bp + (size_t)i*16*ldb + k0);
    #pragma unroll
    for (int mi = 0; mi < 4; mi++)
      #pragma unroll
      for (int ni = 0; ni < 4; ni++)
        acc[mi][ni] = __builtin_amdgcn_mfma_f32_16x16x32_f16(af[mi], bf[ni], acc[mi][ni], 0, 0, 0);
  }
  #pragma unroll
  for (int mi = 0; mi < 4; mi++) {
    #pragma unroll
    for (int ni = 0; ni < 4; ni++) {
      int col = n0 + ni*16 + lr;
      float bv = (MODE == 1) ? 0.f : bias[col];
      #pragma unroll
      for (int r = 0; r < 4; r++) {
        int row = m0 + mi*16 + quad*4 + r;
        if (MODE == 1) {
          ((_Float16*)Cp)[(size_t)row*ldc + col] = (_Float16)acc[mi][ni][r];
        } else {
          ((float*)Cp)[(size_t)row*ldc + col] = acc[mi][ni][r] + bv;
        }
      }
    }
  }
}

// C[b][row][n] = sum_k A[row][k] * imgf[b][n][k]   (fp16 out, ldc=PTLD)
// grid (nx, my, 32): x = n-tile(128), y = m-tile(128), z = b
__global__ void __launch_bounds__(256) gemm_pt_k(const _Float16* __restrict__ A, int lda,
    const _Float16* __restrict__ Bimg, _Float16* __restrict__ Cpt, int mrows) {
  int z = blockIdx.z;
  const _Float16* B = Bimg + (size_t)z*196*512;   // rows >=196 read OOB garbage; masked downstream
  _Float16* C = Cpt + (size_t)z*mrows*PTLD;
  int wave = threadIdx.x >> 6, lane = threadIdx.x & 63;
  int m0 = blockIdx.y*128 + (wave >> 1)*64;
  int n0 = blockIdx.x*128 + (wave & 1)*64;
  int lr = lane & 15, quad = lane >> 4;
  float4_t acc[4][4];
  #pragma unroll
  for (int i = 0; i < 4; i++)
    #pragma unroll
    for (int j = 0; j < 4; j++)
      acc[i][j] = (float4_t){0.f, 0.f, 0.f, 0.f};
  const _Float16* Ap = A + (size_t)(m0 + lr)*lda + quad*8;
  const _Float16* Bp = B + (size_t)(n0 + lr)*512 + quad*8;
  for (int k0 = 0; k0 < 512; k0 += 32) {
    half8_t af[4], bf[4];
    #pragma unroll
    for (int i = 0; i < 4; i++) af[i] = *(const half8_t*)(Ap + (size_t)i*16*lda + k0);
    #pragma unroll
    for (int i = 0; i < 4; i++) bf[i] = *(const half8_t*)(Bp + (size_t)i*16*512 + k0);
    #pragma unroll
    for (int mi = 0; mi < 4; mi++)
      #pragma unroll
      for (int ni = 0; ni < 4; ni++)
        acc[mi][ni] = __builtin_amdgcn_mfma_f32_16x16x32_f16(af[mi], bf[ni], acc[mi][ni], 0, 0, 0);
  }
  #pragma unroll
  for (int mi = 0; mi < 4; mi++) {
    #pragma unroll
    for (int ni = 0; ni < 4; ni++) {
      int col = n0 + ni*16 + lr;
      if (col < PTLD) {
        #pragma unroll
        for (int r = 0; r < 4; r++) {
          int row = m0 + mi*16 + quad*4 + r;
          C[(size_t)row*PTLD + col] = (_Float16)acc[mi][ni][r];
        }
      }
    }
  }
}

// ---- split store/poll barrier, one cacheline per slot ----
// arrive: __syncthreads drains this block's payload stores (vmcnt(0) before
// s_barrier), then one relaxed store publishes the epoch on a private line.
// wait: 8 threads poll 8 private lines in parallel (one IF round trip, no
// serialized line ping-pong). Work placed between arrive and wait overlaps
// the flag propagation.
__device__ __forceinline__ void sbar_arrive(unsigned* __restrict__ slots, int r,
                                            unsigned target, int tid) {
  __syncthreads();
  if (tid == 0) AT_ST(slots + r*BARSTRIDE, target);
}
__device__ __forceinline__ void sbar_wait(unsigned* __restrict__ slots,
                                          unsigned target, int tid) {
  if (tid < 8) {
    while (AT_LD(slots + tid*BARSTRIDE) < target) __builtin_amdgcn_s_sleep(1);
  }
  __syncthreads();
}

// ---- persistent recurrence: 32 groups (one per b) of 8 blocks (one per r-slice) ----
// r = bid & 7 -> same-r blocks share an XCD (Whh/Wdec slices L2-resident).
// 512 threads. Per step, 2 cross-block syncs; Whh gate dot hoisted between
// BAR_E arrive and wait; H/alpha buffered in LDS (no HBM stores in the loop).
__global__ void __launch_bounds__(512) loop_k(
    const _Float16* __restrict__ Wdec_h,   // [512][512]
    const _Float16* __restrict__ Whh_h,    // [2048][512]
    const _Float16* __restrict__ fproj_T,  // [32][512][PTLD]
    const _Float16* __restrict__ P_T,      // [32][2048][PTLD]
    const float*    __restrict__ Xg,       // [64*32][2048]
    const float*    __restrict__ v_att,    // [512]
    const float*    __restrict__ c_init,   // [32][512]
    unsigned*       __restrict__ hpub2,    // [32][256] packed half2 (atomic)
    float*          __restrict__ epub,     // [32][8][256] fp32 partial e (atomic)
    _Float16*       __restrict__ H_h,      // [64*32][512]
    float*          __restrict__ out_alpha,// [32][64][196]
    unsigned*       __restrict__ bar) {
  __shared__ _Float16 P_lds[98*256*2];     // [n2][row][2] half2-interleaved, 100352B
  __shared__ _Float16 fp_lds[64*PTLD];     // fproj_T slice [dloc][n], 25600B
  __shared__ __align__(16) unsigned hl_u[256]; // h as packed half2
  __shared__ _Float16 Hbuf[64*64];         // h slice per step, 8192B
  __shared__ float abuf[25*64];            // alpha slice per step [ln][t], 6400B
  __shared__ float vlf[64];
  __shared__ float hwf[64];
  __shared__ float ep[2][256];
  __shared__ float redA[8];
  __shared__ float redB[8];
  __shared__ float sa[256];
  __shared__ float sm2[512];
  __shared__ float hnl[64];
  int bid = blockIdx.x, tid = threadIdx.x;
  int r = bid & 7, b = bid >> 3;
  unsigned* slots = bar + b*8*BARSTRIDE;
  int row = tid & 255, half = tid >> 8;
  int typ = row >> 6, dl = row & 63;
  int grow = typ*512 + r*64 + dl;          // gate row owned by (thread row)
  int lane = tid & 63;

  if (tid < 64) vlf[tid] = v_att[r*64 + tid];
  float c_reg = (tid < 64) ? c_init[b*512 + r*64 + tid] : 0.f;

  // one-time staging: P rows (tid<256) and fproj_T slice (tid>=256)
  if (tid < 256) {
    const _Float16* pp = P_T + ((size_t)b*2048 + grow)*PTLD;
    half2_t* P2 = (half2_t*)P_lds;
    for (int k8 = 0; k8 < 24; k8++) {
      half8_t v8 = *(const half8_t*)(pp + k8*8);
      #pragma unroll
      for (int j2 = 0; j2 < 4; j2++) {
        half2_t h2; h2[0] = v8[2*j2]; h2[1] = v8[2*j2+1];
        P2[(k8*4 + j2)*256 + row] = h2;
      }
    }
    half4_t v4 = *(const half4_t*)(pp + 192);
    half2_t a2; a2[0] = v4[0]; a2[1] = v4[1];
    half2_t b2; b2[0] = v4[2]; b2[1] = v4[3];
    P2[96*256 + row] = a2;
    P2[97*256 + row] = b2;
  } else {
    for (int i = tid - 256; i < 64*25; i += 256) {
      int d = i/25, c = i - d*25;
      *(half8_t*)(fp_lds + d*PTLD + c*8) =
        *(const half8_t*)(fproj_T + ((size_t)(b*512 + r*64 + d))*PTLD + c*8);
    }
  }
  int eBase = (r < 4) ? r*25 : 100 + (r-4)*24;
  int eCnt  = (r < 4) ? 25 : 24;

  for (int t = 0; t < 64; ++t) {
    // 1. pull published h (tid<256); concurrently issue Xg load (tid>=256)
    if (tid < 256) hl_u[tid] = AT_LD(hpub2 + b*256 + tid);
    float xg = (half == 1) ? Xg[((size_t)t*32 + b)*2048 + grow] : 0.f;
    __syncthreads();
    // 2. hW own slice: thread = dim*8 + s, shfl-reduce over s
    {
      int dim = tid >> 3, s = tid & 7;
      const half8_t* wr = (const half8_t*)(Wdec_h + (size_t)(r*64 + dim)*512 + s*64);
      const half8_t* hh = ((const half8_t*)(const _Float16*)hl_u) + s*8;
      float a = 0.f;
      #pragma unroll
      for (int k8 = 0; k8 < 8; k8++) {
        half8_t w8 = wr[k8]; half8_t h8 = hh[k8];
        const half2_t* wp = (const half2_t*)&w8;
        const half2_t* hp = (const half2_t*)&h8;
        a = fdot2f(wp[0], hp[0], a);
        a = fdot2f(wp[1], hp[1], a);
        a = fdot2f(wp[2], hp[2], a);
        a = fdot2f(wp[3], hp[3], a);
      }
      a += __shfl_xor(a, 1);
      a += __shfl_xor(a, 2);
      a += __shfl_xor(a, 4);
      if (s == 0) hwf[dim] = a;
    }
    __syncthreads();
    // 3. e-partials over own 64 dims: thread = (n=row, dgroup=half)
    {
      float a = 0.f;
      if (row < 196) {
        #pragma unroll 8
        for (int j = 0; j < 32; j++) {
          int dd = half*32 + j;
          a += vlf[dd] * fast_tanh((float)fp_lds[dd*PTLD + row] + hwf[dd]);
        }
      }
      ep[half][row] = a;
    }
    __syncthreads();
    // 4. publish e partial, arrive
    if (tid < 196) AT_ST(epub + ((size_t)b*8 + r)*256 + tid, ep[0][tid] + ep[1][tid]);
    sbar_arrive(slots, r, 2*(unsigned)t + 1, tid);
    // 5. gacc = Xg + Whh[grow].h (split-K) — overlaps flag propagation/skew
    float gacc = xg;
    {
      const half8_t* wr = (const half8_t*)(Whh_h + (size_t)grow*512 + half*256);
      const half8_t* hh = ((const half8_t*)(const _Float16*)hl_u) + half*32;
      for (int k8 = 0; k8 < 32; k8++) {
        half8_t w8 = wr[k8]; half8_t h8 = hh[k8];
        const half2_t* wp = (const half2_t*)&w8;
        const half2_t* hp = (const half2_t*)&h8;
        gacc = fdot2f(wp[0], hp[0], gacc);
        gacc = fdot2f(wp[1], hp[1], gacc);
        gacc = fdot2f(wp[2], hp[2], gacc);
        gacc = fdot2f(wp[3], hp[3], gacc);
      }
    }
    sbar_wait(slots, 2*(unsigned)t + 1, tid);   // BAR_E

    // 6. softmax (replicated): sum the 8 dim-partials, wave-reduce max/sum
    float ee = -1e30f;
    if (tid < 196) {
      float s0 = 0.f;
      #pragma unroll
      for (int rr = 0; rr < 8; rr++)
        s0 += AT_LD(epub + ((size_t)b*8 + rr)*256 + tid);
      ee = s0;
    }
    {
      float m = ee;
      #pragma unroll
      for (int off = 32; off > 0; off >>= 1) m = fmaxf(m, __shfl_xor(m, off));
      if (lane == 0) redA[tid >> 6] = m;
    }
    __syncthreads();
    float mx = redA[0];
    #pragma unroll
    for (int i = 1; i < 8; i++) mx = fmaxf(mx, redA[i]);
    float ex = (tid < 196) ? __expf(ee - mx) : 0.f;
    {
      float s = ex;
      #pragma unroll
      for (int off = 32; off > 0; off >>= 1) s += __shfl_xor(s, off);
      if (lane == 0) redB[tid >> 6] = s;
    }
    __syncthreads();
    float tot = redB[0];
    #pragma unroll
    for (int i = 1; i < 8; i++) tot += redB[i];
    float al = ex * (1.f/tot);
    if (tid < 256) sa[tid] = al;
    if (tid >= eBase && tid < eBase + eCnt)
      abuf[(tid - eBase)*64 + t] = al;           // buffered; written after loop
    __syncthreads();
    // 7. gates: gacc += alpha . P (split-n over halves; P fully LDS-pinned)
    {
      const half2_t* P2 = (const half2_t*)P_lds;
      const float2*  sap = (const float2*)sa;
      int n2b = half*49;
      #pragma unroll 7
      for (int n2 = n2b; n2 < n2b + 49; n2++) {
        half2_t p = P2[n2*256 + row];
        float2 s2 = sap[n2];
        gacc += s2.x*(float)p[0] + s2.y*(float)p[1];
      }
      sm2[tid] = gacc;
    }
    __syncthreads();
    // 8. pointwise LSTM (c in registers); h buffered in LDS
    if (tid < 64) {
      float ig = sm2[tid]       + sm2[tid + 256];
      float fg = sm2[64 + tid]  + sm2[tid + 320];
      float gg = sm2[128 + tid] + sm2[tid + 384];
      float og = sm2[192 + tid] + sm2[tid + 448];
      float cn = fast_sig(fg)*c_reg + fast_sig(ig)*fast_tanh(gg);
      float hn = fast_sig(og)*fast_tanh(cn);
      c_reg = cn;
      hnl[tid] = hn;
      Hbuf[t*64 + tid] = (_Float16)hn;
    }
    __syncthreads();
    // 9. publish packed h slice, arrive, wait
    if (tid < 32) {
      half2_t h2; h2[0] = (_Float16)hnl[2*tid]; h2[1] = (_Float16)hnl[2*tid+1];
      union { half2_t h; unsigned u; } cv; cv.h = h2;
      AT_ST(hpub2 + b*256 + r*32 + tid, cv.u);
    }
    sbar_arrive(slots, r, 2*(unsigned)t + 2, tid);
    sbar_wait(slots, 2*(unsigned)t + 2, tid);   // BAR_H
  }

  // bulk-write buffered H and alpha
  for (int i = tid; i < 64*64; i += 512) {
    int t = i >> 6, d = i & 63;
    H_h[((size_t)t*32 + b)*512 + r*64 + d] = Hbuf[i];
  }
  for (int i = tid; i < eCnt*64; i += 512) {
    int ln = i >> 6, t = i & 63;
    out_alpha[((size_t)b*64 + t)*196 + eBase + ln] = abuf[ln*64 + t];
  }
}

// ---- logits: out[b][t][:] = H[t*32+b] @ Wfc^T + bfc ----
__global__ void __launch_bounds__(512) logits_k(const _Float16* __restrict__ A,
    const _Float16* __restrict__ Bw, float* __restrict__ C,
    const float* __restrict__ bias) {
  int wave = threadIdx.x >> 6, lane = threadIdx.x & 63;
  int lr = lane & 15, quad = lane >> 4;
  int waveM = wave >> 1, waveN = wave & 1;
  int n0 = blockIdx.x*128 + waveN*64;
  const _Float16* Bp = Bw + (size_t)(n0 + lr)*512 + quad*8;
  float bv[4];
  #pragma unroll
  for (int ni = 0; ni < 4; ni++) bv[ni] = bias[n0 + ni*16 + lr];
  for (int it = 0; it < 4; ++it) {
    int m0 = (blockIdx.y*16 + it*4 + waveM)*64;
    const _Float16* Ap = A + (size_t)(m0 + lr)*512 + quad*8;
    float4_t acc[4][4];
    #pragma unroll
    for (int i = 0; i < 4; i++)
      #pragma unroll
      for (int j = 0; j < 4; j++)
        acc[i][j] = (float4_t){0.f, 0.f, 0.f, 0.f};
    for (int k0 = 0; k0 < 512; k0 += 32) {
      half8_t af[4], bf[4];
      #pragma unroll
      for (int i = 0; i < 4; i++) af[i] = *(const half8_t*)(Ap + (size_t)i*16*512 + k0);
      #pragma unroll
      for (int i = 0; i < 4; i++) bf[i] = *(const half8_t*)(Bp + (size_t)i*16*512 + k0);
      #pragma unroll
      for (int mi = 0; mi < 4; mi++)
        #pragma unroll
        for (int ni = 0; ni < 4; ni++)
          acc[mi][ni] = __builtin_amdgcn_mfma_f32_16x16x32_f16(af[mi], bf[ni], acc[mi][ni], 0, 0, 0);
    }
    #pragma unroll
    for (int mi = 0; mi < 4; mi++) {
      #pragma unroll
      for (int ni = 0; ni < 4; ni++) {
        int col = n0 + ni*16 + lr;
        #pragma unroll
        for (int r = 0; r < 4; r++) {
          int row = m0 + mi*16 + quad*4 + r;
          size_t orow = (size_t)((row & 31)*64 + (row >> 5));
          __builtin_nontemporal_store(acc[mi][ni][r] + bv[ni], C + orow*32000 + col);
        }
      }
    }
  }
}

extern "C" void kernel_launch(void* const* d_in, const int* in_sizes, int n_in,
                              void* d_out, int out_size, void* d_ws, size_t ws_size,
                              hipStream_t stream) {
  const float* imgf  = (const float*)d_in[0];
  const int*   cap   = (const int*)d_in[1];
  const float* emb   = (const float*)d_in[2];
  const float* Wh0   = (const float*)d_in[3];
  const float* bh0   = (const float*)d_in[4];
  const float* Wc0   = (const float*)d_in[5];
  const float* bc0   = (const float*)d_in[6];
  const float* Wenc  = (const float*)d_in[7];
  const float* Wdec  = (const float*)d_in[8];
  const float* v_att = (const float*)d_in[9];
  const float* W_ih  = (const float*)d_in[10];
  const float* b_ih  = (const float*)d_in[11];
  const float* W_hh  = (const float*)d_in[12];
  const float* b_hh  = (const float*)d_in[13];
  const float* Wfc   = (const float*)d_in[14];
  const float* bfc   = (const float*)d_in[15];
  float* out = (float*)d_out;
  (void)in_sizes; (void)n_in; (void)out_size; (void)ws_size;

  char* ws = (char*)d_ws;
  size_t off = 0;
  auto alloc = [&](size_t bytes) -> void* {
    void* p = ws + off;
    off += (bytes + 255) & ~(size_t)255;
    return p;
  };
  _Float16* Wenc_h  = (_Float16*)alloc((size_t)512*512*2);
  _Float16* Wdec_h  = (_Float16*)alloc((size_t)512*512*2);
  _Float16* Wih_h   = (_Float16*)alloc((size_t)2048*1024*2);
  _Float16* Whh_h   = (_Float16*)alloc((size_t)2048*512*2);
  _Float16* Wfc_h   = (_Float16*)alloc((size_t)32000*512*2);
  _Float16* imgf_h  = (_Float16*)alloc((size_t)32*196*512*2);
  _Float16* fproj_T = (_Float16*)alloc((size_t)32*512*PTLD*2);
  _Float16* P_T     = (_Float16*)alloc((size_t)32*2048*PTLD*2);
  _Float16* X_h     = (_Float16*)alloc((size_t)64*32*512*2);
  float*    Xg      = (float*)alloc((size_t)64*32*2048*4);
  float*    bsum    = (float*)alloc((size_t)2048*4);
  float*    c_state = (float*)alloc((size_t)32*512*4);
  unsigned* hpub2   = (unsigned*)alloc((size_t)32*256*4);
  float*    epub    = (float*)alloc((size_t)32*8*256*4);
  _Float16* H_h     = (_Float16*)alloc((size_t)2048*512*2);
  unsigned* bar     = (unsigned*)alloc((size_t)32*8*BARSTRIDE*4);

  auto cvt = [&](const float* s, _Float16* d, int n) {
    cvt_k<<<dim3((n/4 + 255)/256), dim3(256), 0, stream>>>(s, d, n);
  };
  cvt(Wenc, Wenc_h, 512*512);
  cvt(Wdec, Wdec_h, 512*512);
  cvt(W_ih, Wih_h, 2048*1024);
  cvt(W_hh, Whh_h, 2048*512);
  cvt(Wfc,  Wfc_h, 32000*512);
  cvt(imgf, imgf_h, 32*196*512);
  bias_sum_k<<<dim3(8), dim3(256), 0, stream>>>(b_ih, b_hh, bsum, bar);
  gather_emb_k<<<dim3(2048), dim3(256), 0, stream>>>(emb, cap, X_h);
  init_state_k<<<dim3(32), dim3(256), 0, stream>>>(imgf, Wh0, bh0, Wc0, bc0, c_state, hpub2);
  // fproj_T[b] = Wenc @ imgf[b]^T -> fp16 [32][512][PTLD]
  gemm_pt_k<<<dim3(2, 4, 32), dim3(256), 0, stream>>>(Wenc_h, 512, imgf_h, fproj_T, 512);
  // P_T[b] = W_ih[:,512:] @ imgf[b]^T -> fp16 [32][2048][PTLD]
  gemm_pt_k<<<dim3(2, 16, 32), dim3(256), 0, stream>>>(Wih_h + 512, 1024, imgf_h, P_T, 2048);
  // Xg = emb_x @ W_ih[:, :512]^T + (b_ih + b_hh)  -> fp32 [2048, 2048]
  gemm_abt_k<0><<<dim3(16, 16), dim3(256), 0, stream>>>(X_h, 512, Wih_h, 1024, Xg, 2048, bsum, 512);

  float* out_alpha = out + (size_t)32*64*32000;
  // all 64 recurrence steps in one persistent launch (32 groups x 8 blocks, 512 thr)
  loop_k<<<dim3(256), dim3(512), 0, stream>>>(Wdec_h, Whh_h, fproj_T, P_T, Xg,
      v_att, c_state, hpub2, epub, H_h, out_alpha, bar);
  // outputs = H @ Wfc^T + bfc (remapped rows)
  logits_k<<<dim3(250, 2), dim3(512), 0, stream>>>(H_h, Wfc_h, out, bfc);
}